// Round 6
// baseline (752.686 us; speedup 1.0000x reference)
//
#include <hip/hip_runtime.h>
#include <hip/hip_bf16.h>
#include <hip/hip_cooperative_groups.h>
#include <math.h>

namespace cg = cooperative_groups;

#define NN 20000
#define EE 320000
#define IND 128
#define HH 6
#define CC 64
#define HCC 384
#define NCC 16
#define NGG 64

typedef __bf16 bf16x8 __attribute__((ext_vector_type(8)));
typedef float f32x4 __attribute__((ext_vector_type(4)));
typedef float f32x2 __attribute__((ext_vector_type(2)));
typedef unsigned short ushort_t;
typedef unsigned int uint_t;

#define LOG2E 1.44269504088896f

__device__ inline ushort_t f2bf(float f) {
    union { float f; uint_t u; } x; x.f = f;
    uint_t r = (x.u + 0x7FFF + ((x.u >> 16) & 1)) >> 16;
    return (ushort_t)r;
}
// 8 packed bf16 (uint4) -> 4 f32x2 (pairs) for packed-f32 VALU
__device__ inline void bf8cvt2(uint4 v, f32x2* f) {
    union { uint_t u; float x; } a, b;
    a.u = v.x << 16; b.u = v.x & 0xFFFF0000u; f[0] = (f32x2){a.x, b.x};
    a.u = v.y << 16; b.u = v.y & 0xFFFF0000u; f[1] = (f32x2){a.x, b.x};
    a.u = v.z << 16; b.u = v.z & 0xFFFF0000u; f[2] = (f32x2){a.x, b.x};
    a.u = v.w << 16; b.u = v.w & 0xFFFF0000u; f[3] = (f32x2){a.x, b.x};
}

// DPP cross-lane add (VALU, no DS pipe). CTRL: 0xB1=xor1, 0x4E=xor2,
// 0x141=row_half_mirror (==xor4 once quad-uniform), 0x140=row_mirror (==xor8).
template <int CTRL>
__device__ inline float dppadd(float x) {
    int y = __builtin_amdgcn_mov_dpp(__builtin_bit_cast(int, x), CTRL, 0xF, 0xF, true);
    return x + __builtin_bit_cast(float, y);
}

// async global->LDS: lane L writes lds+16*L
__device__ inline void load_lds16(const ushort_t* g, ushort_t* l) {
    __builtin_amdgcn_global_load_lds(
        (const __attribute__((address_space(1))) void*)g,
        (__attribute__((address_space(3))) void*)l, 16, 0, 0);
}

// ---------------- weight/input prep element (fp32 -> bf16 TRANSPOSED [N][K]) ----------------
#define WBIG (1152 * IND)
#define WC1 (768 * HCC)
#define WC2 (192 * HCC)
#define XB_N (NN * IND)
#define PREP_TOTAL (WBIG + WC1 + WC2 + XB_N + 1152 + 768 + 192)

__device__ inline void prep_elem(int i,
    const float* __restrict__ x, const float* __restrict__ inp_w,
    const float* __restrict__ l0wl, const float* __restrict__ l0wr,
    const float* __restrict__ l1wl, const float* __restrict__ l1wr,
    const float* __restrict__ l2wl, const float* __restrict__ l2wr,
    const float* __restrict__ resw,
    const float* __restrict__ inp_b,
    const float* __restrict__ l0bl, const float* __restrict__ l0br,
    const float* __restrict__ l1bl, const float* __restrict__ l1br,
    const float* __restrict__ l2bl, const float* __restrict__ l2br,
    ushort_t* wBig, ushort_t* wC1, ushort_t* wC2, ushort_t* xb,
    float* bBig, float* bC1, float* bC2)
{
    if (i < WBIG) {
        int col = i >> 7, k = i & 127;
        float v;
        if (col < 384)      v = inp_w[k * 384 + col];
        else if (col < 768) v = l0wl[k * 384 + (col - 384)];
        else                v = l0wr[k * 384 + (col - 768)];
        wBig[i] = f2bf(v); return;
    }
    i -= WBIG;
    if (i < WC1) {
        int col = i / 384, k = i - col * 384;
        float v = col < 384 ? l1wl[k * 384 + col] : l1wr[k * 384 + (col - 384)];
        wC1[i] = f2bf(v); return;
    }
    i -= WC1;
    if (i < WC2) {
        int col = i / 384, k = i - col * 384;
        float v;
        if (col < 64)       v = resw[k * 64 + col];
        else if (col < 128) v = l2wl[k * 64 + (col - 64)];
        else                v = l2wr[k * 64 + (col - 128)];
        wC2[i] = f2bf(v); return;
    }
    i -= WC2;
    if (i < XB_N) { xb[i] = f2bf(x[i]); return; }
    i -= XB_N;
    if (i < 1152) {
        float v;
        if (i < 384)      v = inp_b[i];
        else if (i < 768) v = l0bl[i - 384];
        else              v = l0br[i - 768];
        bBig[i] = v; return;
    }
    i -= 1152;
    if (i < 768) { bC1[i] = i < 384 ? l1bl[i] : l1br[i - 384]; return; }
    i -= 768;
    if (i < 192) {
        float v;
        if (i < 64)       v = 0.0f;
        else if (i < 128) v = l2bl[i - 64];
        else              v = l2br[i - 128];
        bC2[i] = v; return;
    }
}

// ---------------- fused preprocessing: zero + prep + count + scan + fill ----------------
// ONE cooperative kernel replaces 5 launches (each launch gap ~2-10us in this harness).
// 512 blocks x 256 thr = 131072 threads (25% of chip capacity -> co-resident for sure).
// Scan: two-level distributed (1 elem/thread block-scan -> block0 scans 512 partials).
__global__ __launch_bounds__(256) void pre_kernel(
    const float* __restrict__ x, const float* __restrict__ inp_w,
    const float* __restrict__ l0wl, const float* __restrict__ l0wr,
    const float* __restrict__ l1wl, const float* __restrict__ l1wr,
    const float* __restrict__ l2wl, const float* __restrict__ l2wr,
    const float* __restrict__ resw,
    const float* __restrict__ inp_b,
    const float* __restrict__ l0bl, const float* __restrict__ l0br,
    const float* __restrict__ l1bl, const float* __restrict__ l1br,
    const float* __restrict__ l2bl, const float* __restrict__ l2br,
    const int* __restrict__ ei,
    ushort_t* wBig, ushort_t* wC1, ushort_t* wC2, ushort_t* xb,
    float* bBig, float* bC1, float* bC2,
    int* counts, int* offsets, int* cursor, int* srcs,
    int* blockSums, int* blockBase)
{
    cg::grid_group g = cg::this_grid();
    const int TOT = gridDim.x * blockDim.x;          // 131072
    int tid = blockIdx.x * blockDim.x + threadIdx.x;
    int lt = threadIdx.x, bid = blockIdx.x;
    __shared__ int lp[256];

    // ---- P1: zero counts + srcs pad, prep weights/x ----
    for (int i = tid; i < NN; i += TOT) counts[i] = 0;
    if (tid < 8) srcs[EE + NN + tid] = 0;
    for (int i = tid; i < PREP_TOTAL; i += TOT)
        prep_elem(i, x, inp_w, l0wl, l0wr, l1wl, l1wr, l2wl, l2wr, resw,
                  inp_b, l0bl, l0br, l1bl, l1br, l2bl, l2br,
                  wBig, wC1, wC2, xb, bBig, bC1, bC2);
    g.sync();

    // ---- P2: count in-degrees ----
    for (int t = tid; t < EE; t += TOT) atomicAdd(&counts[ei[EE + t]], 1);
    g.sync();

    // ---- P3a: block-local exclusive scan of (counts[i]+1), 1 elem/thread ----
    int v = (tid < NN) ? counts[tid] + 1 : 0;
    lp[lt] = v;
    __syncthreads();
    for (int o = 1; o < 256; o <<= 1) {
        int u = (lt >= o) ? lp[lt - o] : 0;
        __syncthreads();
        lp[lt] += u;
        __syncthreads();
    }
    int incl = lp[lt];
    if (lt == 255) blockSums[bid] = incl;
    int lexcl = incl - v;
    g.sync();

    // ---- P3b: block 0 scans 512 block sums (2/thread) ----
    if (bid == 0) {
        int s0 = blockSums[2 * lt], s1 = blockSums[2 * lt + 1];
        lp[lt] = s0 + s1;
        __syncthreads();
        for (int o = 1; o < 256; o <<= 1) {
            int u = (lt >= o) ? lp[lt - o] : 0;
            __syncthreads();
            lp[lt] += u;
            __syncthreads();
        }
        int pincl = lp[lt];
        int pexcl = pincl - (s0 + s1);
        blockBase[2 * lt] = pexcl;
        blockBase[2 * lt + 1] = pexcl + s0;
        if (lt == 255) offsets[NN] = pincl;
    }
    g.sync();

    // ---- P3c: write offsets/cursor ----
    if (tid < NN) {
        int val = blockBase[bid] + lexcl;
        offsets[tid] = val;
        cursor[tid] = val;
    }
    g.sync();

    // ---- P4: fill srcs (stores s<<8; gat6 derives *6, gat1 uses directly) ----
    for (int t = tid; t < EE + NN; t += TOT) {
        int s, d;
        if (t < EE) { s = ei[t]; d = ei[EE + t]; }
        else        { s = t - EE; d = s; }
        int slot = atomicAdd(&cursor[d], 1);
        srcs[slot] = s << 8;
    }
}

// ---------------- bf16 MFMA GEMM (big): M-tile 256, 8 waves, in-kernel col-tile loop ----
__global__ __launch_bounds__(512) void gemm_mfma2(
    const ushort_t* __restrict__ A, const ushort_t* __restrict__ BT,
    const float* __restrict__ bias,
    ushort_t* __restrict__ Cb1, int ld1,
    ushort_t* __restrict__ Cb2, int ld2, int split,
    int M, int N, int K, int NT)
{
    __shared__ ushort_t Bs[2][2][128 * 32];   // 32 KB
    int t = threadIdx.x;
    int w = t >> 6, L = t & 63;               // w in [0,8)
    int m0 = blockIdx.x * 256;
    int q = L >> 4, r16 = L & 15;
    int lr = L >> 2;
    int lc = ((L & 3) ^ ((lr >> 1) & 3)) * 8;   // pre-swizzled source chunk
    int sw = (q ^ ((r16 >> 1) & 3)) * 8;        // matching ds_read swizzle
    int oB = (w * 16) * 32;                     // wave stages B rows [w*16, w*16+16)

    int rA0 = min(m0 + w * 32 + r16, M - 1);
    int rA1 = min(m0 + w * 32 + 16 + r16, M - 1);
    const ushort_t* pA0base = A + (size_t)rA0 * K + q * 8;
    const ushort_t* pA1base = A + (size_t)rA1 * K + q * 8;

    for (int nt = 0; nt < NT; ++nt) {
        int n0 = (blockIdx.y * NT + nt) * 128;
        int rB = min(n0 + w * 16 + lr, N - 1);
        const ushort_t* gB = BT + (size_t)rB * K + lc;
        const ushort_t* pA0 = pA0base;
        const ushort_t* pA1 = pA1base;

        f32x4 acc[2][8];
#pragma unroll
        for (int a = 0; a < 2; ++a)
#pragma unroll
            for (int b = 0; b < 8; ++b) acc[a][b] = (f32x4){0.f, 0.f, 0.f, 0.f};

        load_lds16(gB, &Bs[0][0][oB]);
        load_lds16(gB + 32, &Bs[0][1][oB]);
        gB += 64;
        bf16x8 a0 = *(const bf16x8*)pA0;
        bf16x8 a2 = *(const bf16x8*)(pA0 + 32);
        bf16x8 a1 = *(const bf16x8*)pA1;
        bf16x8 a3 = *(const bf16x8*)(pA1 + 32);
        pA0 += 64; pA1 += 64;

        int buf = 0;
        for (int k0 = 0; k0 < K; k0 += 64) {
            __syncthreads();
            bool more = (k0 + 64 < K);
            if (more) {
                int nb = buf ^ 1;
                load_lds16(gB, &Bs[nb][0][oB]);
                load_lds16(gB + 32, &Bs[nb][1][oB]);
                gB += 64;
            }
            bf16x8 na0, na1, na2, na3;
            if (more) {
                na0 = *(const bf16x8*)pA0;
                na2 = *(const bf16x8*)(pA0 + 32);
                na1 = *(const bf16x8*)pA1;
                na3 = *(const bf16x8*)(pA1 + 32);
                pA0 += 64; pA1 += 64;
            }
#pragma unroll
            for (int ct = 0; ct < 8; ++ct) {
                bf16x8 blo = *(const bf16x8*)&Bs[buf][0][(ct * 16 + r16) * 32 + sw];
                bf16x8 bhi = *(const bf16x8*)&Bs[buf][1][(ct * 16 + r16) * 32 + sw];
                acc[0][ct] = __builtin_amdgcn_mfma_f32_16x16x32_bf16(blo, a0, acc[0][ct], 0, 0, 0);
                acc[1][ct] = __builtin_amdgcn_mfma_f32_16x16x32_bf16(blo, a1, acc[1][ct], 0, 0, 0);
                acc[0][ct] = __builtin_amdgcn_mfma_f32_16x16x32_bf16(bhi, a2, acc[0][ct], 0, 0, 0);
                acc[1][ct] = __builtin_amdgcn_mfma_f32_16x16x32_bf16(bhi, a3, acc[1][ct], 0, 0, 0);
            }
            if (more) { a0 = na0; a1 = na1; a2 = na2; a3 = na3; }
            buf ^= 1;
        }
#pragma unroll
        for (int rt = 0; rt < 2; ++rt) {
            int row = m0 + w * 32 + rt * 16 + r16;
            if (row >= M) continue;
#pragma unroll
            for (int ct = 0; ct < 8; ++ct) {
                int colb = n0 + ct * 16 + q * 4;
                if (colb >= N) continue;
                float4 bv = *(const float4*)(bias + colb);
                uint2 pk;
                pk.x = (uint_t)f2bf(acc[rt][ct][0] + bv.x) | ((uint_t)f2bf(acc[rt][ct][1] + bv.y) << 16);
                pk.y = (uint_t)f2bf(acc[rt][ct][2] + bv.z) | ((uint_t)f2bf(acc[rt][ct][3] + bv.w) << 16);
                if (colb < split)
                    *(uint2*)(Cb1 + (size_t)row * ld1 + colb) = pk;
                else
                    *(uint2*)(Cb2 + (size_t)row * ld2 + (colb - split)) = pk;
            }
        }
    }
}

// ---------------- bf16 MFMA GEMM (small, 128-tile): kept for gemm3 ----------------
__global__ __launch_bounds__(256) void gemm_mfma(
    const ushort_t* __restrict__ A, const ushort_t* __restrict__ BT,
    const float* __restrict__ bias,
    float* __restrict__ Cf, ushort_t* __restrict__ Cb1, int ld1,
    ushort_t* __restrict__ Cb2, int ld2, int split,
    int M, int N, int K)
{
    __shared__ ushort_t Bs[2][2][128 * 32];
    int t = threadIdx.x;
    int w = t >> 6, L = t & 63;
    int m0 = blockIdx.x * 128, n0 = blockIdx.y * 128;
    int q = L >> 4, r16 = L & 15;

    f32x4 acc[2][8];
#pragma unroll
    for (int a = 0; a < 2; ++a)
#pragma unroll
        for (int b = 0; b < 8; ++b) acc[a][b] = (f32x4){0.f, 0.f, 0.f, 0.f};

    int lr = L >> 2;
    int lc = ((L & 3) ^ ((lr >> 1) & 3)) * 8;
    int rB0 = min(n0 + w * 32 + lr, N - 1);
    int rB1 = min(n0 + w * 32 + 16 + lr, N - 1);
    const ushort_t* gB0 = BT + (size_t)rB0 * K + lc;
    const ushort_t* gB1 = BT + (size_t)rB1 * K + lc;
    int oB0 = (w * 32) * 32;
    int oB1 = (w * 32 + 16) * 32;

    int rA0 = min(m0 + w * 32 + r16, M - 1);
    int rA1 = min(m0 + w * 32 + 16 + r16, M - 1);
    const ushort_t* pA0 = A + (size_t)rA0 * K + q * 8;
    const ushort_t* pA1 = A + (size_t)rA1 * K + q * 8;

    int sw = (q ^ ((r16 >> 1) & 3)) * 8;

    load_lds16(gB0, &Bs[0][0][oB0]);
    load_lds16(gB1, &Bs[0][0][oB1]);
    load_lds16(gB0 + 32, &Bs[0][1][oB0]);
    load_lds16(gB1 + 32, &Bs[0][1][oB1]);
    gB0 += 64; gB1 += 64;
    bf16x8 a0 = *(const bf16x8*)pA0;
    bf16x8 a2 = *(const bf16x8*)(pA0 + 32);
    bf16x8 a1 = *(const bf16x8*)pA1;
    bf16x8 a3 = *(const bf16x8*)(pA1 + 32);
    pA0 += 64; pA1 += 64;

    int buf = 0;
    for (int k0 = 0; k0 < K; k0 += 64) {
        __syncthreads();
        bool more = (k0 + 64 < K);
        if (more) {
            int nb = buf ^ 1;
            load_lds16(gB0, &Bs[nb][0][oB0]);
            load_lds16(gB1, &Bs[nb][0][oB1]);
            load_lds16(gB0 + 32, &Bs[nb][1][oB0]);
            load_lds16(gB1 + 32, &Bs[nb][1][oB1]);
            gB0 += 64; gB1 += 64;
        }
        bf16x8 na0, na1, na2, na3;
        if (more) {
            na0 = *(const bf16x8*)pA0;
            na2 = *(const bf16x8*)(pA0 + 32);
            na1 = *(const bf16x8*)pA1;
            na3 = *(const bf16x8*)(pA1 + 32);
            pA0 += 64; pA1 += 64;
        }
#pragma unroll
        for (int ct = 0; ct < 8; ++ct) {
            bf16x8 blo = *(const bf16x8*)&Bs[buf][0][(ct * 16 + r16) * 32 + sw];
            bf16x8 bhi = *(const bf16x8*)&Bs[buf][1][(ct * 16 + r16) * 32 + sw];
            acc[0][ct] = __builtin_amdgcn_mfma_f32_16x16x32_bf16(blo, a0, acc[0][ct], 0, 0, 0);
            acc[1][ct] = __builtin_amdgcn_mfma_f32_16x16x32_bf16(blo, a1, acc[1][ct], 0, 0, 0);
            acc[0][ct] = __builtin_amdgcn_mfma_f32_16x16x32_bf16(bhi, a2, acc[0][ct], 0, 0, 0);
            acc[1][ct] = __builtin_amdgcn_mfma_f32_16x16x32_bf16(bhi, a3, acc[1][ct], 0, 0, 0);
        }
        if (more) { a0 = na0; a1 = na1; a2 = na2; a3 = na3; }
        buf ^= 1;
    }
#pragma unroll
    for (int rt = 0; rt < 2; ++rt) {
        int row = m0 + w * 32 + rt * 16 + r16;
        if (row >= M) continue;
#pragma unroll
        for (int ct = 0; ct < 8; ++ct) {
            int colb = n0 + ct * 16 + q * 4;
            if (colb >= N) continue;
            float4 bv = *(const float4*)(bias + colb);
            float v0 = acc[rt][ct][0] + bv.x;
            float v1 = acc[rt][ct][1] + bv.y;
            float v2 = acc[rt][ct][2] + bv.z;
            float v3 = acc[rt][ct][3] + bv.w;
            if (colb < split) {
                if (Cf) {
                    *(float4*)(Cf + (size_t)row * ld1 + colb) = make_float4(v0, v1, v2, v3);
                } else {
                    uint2 pk;
                    pk.x = (uint_t)f2bf(v0) | ((uint_t)f2bf(v1) << 16);
                    pk.y = (uint_t)f2bf(v2) | ((uint_t)f2bf(v3) << 16);
                    *(uint2*)(Cb1 + (size_t)row * ld1 + colb) = pk;
                }
            } else {
                uint2 pk;
                pk.x = (uint_t)f2bf(v0) | ((uint_t)f2bf(v1) << 16);
                pk.y = (uint_t)f2bf(v2) | ((uint_t)f2bf(v3) << 16);
                *(uint2*)(Cb2 + (size_t)row * ld2 + (colb - split)) = pk;
            }
        }
    }
}

// ---------------- GATv2 H=6: branchless 1-deep pair loop, srcs stores s<<8 ----------------
__global__ __launch_bounds__(128) void gat6_kernel(
    const ushort_t* __restrict__ cat, const float* __restrict__ att,
    const float* __restrict__ bias, const ushort_t* __restrict__ resB,
    ushort_t* __restrict__ outB,
    const int* __restrict__ offsets, const int* __restrict__ srcs, int n)
{
    int wid = (blockIdx.x * blockDim.x + threadIdx.x) >> 6;
    if (wid >= n) return;
    int lane = threadIdx.x & 63;
    int h = lane >> 3, c8 = lane & 7;
    bool hv = h < HH;
    int off = h * 64 + c8 * 8;
    int offL2 = (hv ? off : off - 384) * 2;   // BYTE offset; invalid lanes alias groups 0/1
    int i = wid;
    int beg = __builtin_amdgcn_readfirstlane(offsets[i]);
    int end = __builtin_amdgcn_readfirstlane(offsets[i + 1]);
    int deg = end - beg;
    int P = (deg + 1) >> 1;
    const char* catc = (const char*)cat;

    f32x2 xr2[4], att2[4];
    {
        uint4 v = *(const uint4*)(catc + (size_t)i * 1536 + 768 + offL2);
        bf8cvt2(v, xr2);
    }
#pragma unroll
    for (int j = 0; j < 4; ++j) {
        int o = (offL2 >> 1) + 2 * j;
        att2[j] = (f32x2){att[o] * LOG2E, att[o + 1] * LOG2E};
    }

    float s = 0.0f;
    f32x2 acc2[4];
#pragma unroll
    for (int j = 0; j < 4; ++j) acc2[j] = (f32x2){0.f, 0.f};

    // srcs[k] = src<<8 ; *6 gives byte offset for 1536 B rows (2 shifts+add, off crit path)
    int bA0 = srcs[beg] * 6, bB0 = srcs[beg + 1] * 6;
    uint4 cA = *(const uint4*)(catc + (size_t)(uint_t)bA0 + offL2);
    uint4 cB = *(const uint4*)(catc + (size_t)(uint_t)bB0 + offL2);
    int iA1 = srcs[beg + 2] * 6, iB1 = srcs[beg + 3] * 6;

    for (int p = 0; p < P; ++p) {
        uint4 nA = cA, nB = cB;
        bool pre = (p + 1 < P);       // uniform branch: skip useless last prefetch
        if (pre) {
            nA = *(const uint4*)(catc + (size_t)(uint_t)iA1 + offL2);
            nB = *(const uint4*)(catc + (size_t)(uint_t)iB1 + offL2);
            iA1 = srcs[beg + 2 * p + 4] * 6;
            iB1 = srcs[beg + 2 * p + 5] * 6;
        }
        f32x2 xlA[4], xlB[4];
        bf8cvt2(cA, xlA);
        bf8cvt2(cB, xlB);
        f32x2 pA2 = (f32x2){0.f, 0.f}, pB2 = (f32x2){0.f, 0.f};
#pragma unroll
        for (int j = 0; j < 4; ++j) {
            f32x2 ta = xlA[j] + xr2[j];
            ta = __builtin_elementwise_max(ta, ta * 0.2f);
            pA2 += ta * att2[j];
            f32x2 tb = xlB[j] + xr2[j];
            tb = __builtin_elementwise_max(tb, tb * 0.2f);
            pB2 += tb * att2[j];
        }
        float pA = pA2.x + pA2.y, pB = pB2.x + pB2.y;
        pA = dppadd<0xB1>(pA);
        pB = dppadd<0xB1>(pB);
        pA = dppadd<0x4E>(pA);
        pB = dppadd<0x4E>(pB);
        pA = dppadd<0x141>(pA);
        pB = dppadd<0x141>(pB);
        float wA = __builtin_amdgcn_exp2f(pA);
        float wB = (2 * p + 1 < deg) ? __builtin_amdgcn_exp2f(pB) : 0.0f;
        s += wA + wB;
        f32x2 wA2 = (f32x2){wA, wA}, wB2 = (f32x2){wB, wB};
#pragma unroll
        for (int j = 0; j < 4; ++j) {
            acc2[j] += wA2 * xlA[j];
            acc2[j] += wB2 * xlB[j];
        }
        cA = nA; cB = nB;
    }

    if (hv) {
        float inv = 1.0f / (s + 1e-16f);
        size_t ob = (size_t)i * HCC + off;
        uint4 rv = *(const uint4*)(resB + ob);
        f32x2 rr[4];
        bf8cvt2(rv, rr);
        ushort_t u[8];
#pragma unroll
        for (int j = 0; j < 4; ++j) {
            float v0 = acc2[j].x * inv + bias[off + 2 * j];
            float v1 = acc2[j].y * inv + bias[off + 2 * j + 1];
            v0 = v0 > 0.0f ? v0 : expm1f(v0);
            v1 = v1 > 0.0f ? v1 : expm1f(v1);
            u[2 * j]     = f2bf(v0 + rr[j].x);
            u[2 * j + 1] = f2bf(v1 + rr[j].y);
        }
        *(uint4*)(outB + ob) = *(uint4*)u;
    }
}

// ---------------- GATv2 H=1: single-pass exp2-folded, DPP reduce, srcs = s<<8 ----------------
__global__ __launch_bounds__(128) void gat1_kernel(
    const ushort_t* __restrict__ cat, const float* __restrict__ att,
    const float* __restrict__ bias, const float* __restrict__ res,
    float* __restrict__ out,
    const int* __restrict__ offsets, const int* __restrict__ srcs, int n)
{
    int wid = (blockIdx.x * blockDim.x + threadIdx.x) >> 6;
    if (wid >= n) return;
    int lane = threadIdx.x & 63;
    int e8 = lane >> 3, c8 = lane & 7;
    int i = wid;
    int beg = __builtin_amdgcn_readfirstlane(offsets[i]);
    int end = __builtin_amdgcn_readfirstlane(offsets[i + 1]);
    const char* catc = (const char*)cat;

    f32x2 xr2[4], att2[4];
    {
        uint4 v = *(const uint4*)(cat + (size_t)i * 128 + 64 + c8 * 8);
        bf8cvt2(v, xr2);
    }
#pragma unroll
    for (int j = 0; j < 4; ++j)
        att2[j] = (f32x2){att[c8 * 8 + 2 * j] * LOG2E, att[c8 * 8 + 2 * j + 1] * LOG2E};

    float s = 0.0f;
    f32x2 acc2[4];
#pragma unroll
    for (int j = 0; j < 4; ++j) acc2[j] = (f32x2){0.f, 0.f};

    const uint4 z = make_uint4(0u, 0u, 0u, 0u);
    int p = beg + e8;
    bool val = p < end;
    int b = val ? srcs[p] : (i << 8);
    uint4 v = *(const uint4*)(catc + (size_t)(uint_t)b + c8 * 16);

    for (int p0 = beg; p0 < end; p0 += 8) {
        uint4 nv = z;
        bool nval = false;
        if (p0 + 8 < end) {
            int np = p0 + 8 + e8;
            nval = np < end;
            int nb = nval ? srcs[np] : (i << 8);
            nv = *(const uint4*)(catc + (size_t)(uint_t)nb + c8 * 16);
        }
        f32x2 xl[4];
        bf8cvt2(v, xl);
        f32x2 pp2 = (f32x2){0.f, 0.f};
#pragma unroll
        for (int j = 0; j < 4; ++j) {
            f32x2 tv = xl[j] + xr2[j];
            tv = __builtin_elementwise_max(tv, tv * 0.2f);
            pp2 += tv * att2[j];
        }
        float partial = pp2.x + pp2.y;
        partial = dppadd<0xB1>(partial);
        partial = dppadd<0x4E>(partial);
        partial = dppadd<0x141>(partial);
        float wE = val ? __builtin_amdgcn_exp2f(partial) : 0.0f;
        s += wE;
        f32x2 w2 = (f32x2){wE, wE};
#pragma unroll
        for (int j = 0; j < 4; ++j) acc2[j] += w2 * xl[j];
        v = nv;
        val = nval;
    }

    s = dppadd<0x140>(s);
    s += __shfl_xor(s, 16, 64);
    s += __shfl_xor(s, 32, 64);
#pragma unroll
    for (int j = 0; j < 4; ++j) {
        acc2[j].x += __shfl_xor(acc2[j].x, 8, 64);
        acc2[j].y += __shfl_xor(acc2[j].y, 8, 64);
        acc2[j].x += __shfl_xor(acc2[j].x, 16, 64);
        acc2[j].y += __shfl_xor(acc2[j].y, 16, 64);
        acc2[j].x += __shfl_xor(acc2[j].x, 32, 64);
        acc2[j].y += __shfl_xor(acc2[j].y, 32, 64);
    }
    if (e8 == 0) {
        float inv = 1.0f / (s + 1e-16f);
        size_t ob = (size_t)i * CC + c8 * 8;
        float4 r0 = *(const float4*)(res + ob);
        float4 r1 = *(const float4*)(res + ob + 4);
        float rr[8] = {r0.x, r0.y, r0.z, r0.w, r1.x, r1.y, r1.z, r1.w};
        float av[8] = {acc2[0].x, acc2[0].y, acc2[1].x, acc2[1].y,
                       acc2[2].x, acc2[2].y, acc2[3].x, acc2[3].y};
#pragma unroll
        for (int j = 0; j < 8; ++j) {
            float v2 = av[j] * inv + bias[c8 * 8 + j];
            v2 = v2 > 0.0f ? v2 : expm1f(v2);
            av[j] = v2 + rr[j];
        }
        *(float4*)(out + ob) = make_float4(av[0], av[1], av[2], av[3]);
        *(float4*)(out + ob + 4) = make_float4(av[4], av[5], av[6], av[7]);
    }
}

// ---------------- pooling: one block per group (batch sorted), no atomics ----------------
__global__ __launch_bounds__(256) void pool_kernel(const float* __restrict__ h,
                                                   const int* __restrict__ batch,
                                                   float* __restrict__ pooled, int n) {
    int g = blockIdx.x;            // NG blocks
    int t = threadIdx.x;           // 256
    int w = t >> 6, lane = t & 63;
    int lo = 0, hi = n;
    while (lo < hi) { int mid = (lo + hi) >> 1; if (batch[mid] < g) lo = mid + 1; else hi = mid; }
    int start = lo;
    int hi2 = n;
    while (lo < hi2) { int mid = (lo + hi2) >> 1; if (batch[mid] < g + 1) lo = mid + 1; else hi2 = mid; }
    int endd = lo;
    float acc = 0.0f;
    for (int r = start + w; r < endd; r += 4)
        acc += h[(size_t)r * 64 + lane];
    __shared__ float red[4][64];
    red[w][lane] = acc;
    __syncthreads();
    if (w == 0)
        pooled[g * 64 + lane] = red[0][lane] + red[1][lane] + red[2][lane] + red[3][lane];
}

// ---------------- dense head ----------------
__global__ void head_kernel(const float* __restrict__ pooled,
                            const float* __restrict__ d1w, const float* __restrict__ d1b,
                            const float* __restrict__ bng, const float* __restrict__ bnb,
                            const float* __restrict__ bnm, const float* __restrict__ bnv,
                            const float* __restrict__ d2w, const float* __restrict__ d2b,
                            float* __restrict__ zout) {
    __shared__ float z1[64 * 64];
    int t = threadIdx.x;  // 256
    for (int idx = t; idx < 64 * 64; idx += 256) {
        int r = idx >> 6, c = idx & 63;
        float acc = d1b[c];
        for (int k = 0; k < 64; ++k) acc += pooled[r * 64 + k] * d1w[k * 64 + c];
        acc = (acc - bnm[c]) / sqrtf(bnv[c] + 1e-5f) * bng[c] + bnb[c];
        z1[idx] = acc > 0.0f ? acc : 0.0f;
    }
    __syncthreads();
    for (int idx = t; idx < 64 * NCC; idx += 256) {
        int r = idx >> 4, c = idx & 15;
        float acc = d2b[c];
        for (int k = 0; k < 64; ++k) acc += z1[r * 64 + k] * d2w[k * NCC + c];
        zout[idx] = acc;
    }
}

// ---------------- launcher ----------------

extern "C" void kernel_launch(void* const* d_in, const int* in_sizes, int n_in,
                              void* d_out, int out_size, void* d_ws, size_t ws_size,
                              hipStream_t stream) {
    const int N = NN, E = EE, C = CC, HC = HCC, NG = NGG;
    const int EN = E + N;

    const float* x     = (const float*)d_in[0];
    const int*   ei    = (const int*)d_in[1];
    const int*   batch = (const int*)d_in[2];
    const float* inp_w = (const float*)d_in[3];
    const float* inp_b = (const float*)d_in[4];
    const float* l0_wl = (const float*)d_in[5];
    const float* l0_bl = (const float*)d_in[6];
    const float* l0_wr = (const float*)d_in[7];
    const float* l0_br = (const float*)d_in[8];
    const float* l0_att = (const float*)d_in[9];
    const float* l0_bias = (const float*)d_in[10];
    const float* l1_wl = (const float*)d_in[11];
    const float* l1_bl = (const float*)d_in[12];
    const float* l1_wr = (const float*)d_in[13];
    const float* l1_br = (const float*)d_in[14];
    const float* l1_att = (const float*)d_in[15];
    const float* l1_bias = (const float*)d_in[16];
    const float* l2_wl = (const float*)d_in[17];
    const float* l2_bl = (const float*)d_in[18];
    const float* l2_wr = (const float*)d_in[19];
    const float* l2_br = (const float*)d_in[20];
    const float* l2_att = (const float*)d_in[21];
    const float* l2_bias = (const float*)d_in[22];
    const float* res_w = (const float*)d_in[23];
    const float* d1_w = (const float*)d_in[24];
    const float* d1_b = (const float*)d_in[25];
    const float* bn_g = (const float*)d_in[26];
    const float* bn_b = (const float*)d_in[27];
    const float* bn_m = (const float*)d_in[28];
    const float* bn_v = (const float*)d_in[29];
    const float* d2_w = (const float*)d_in[30];
    const float* d2_b = (const float*)d_in[31];

    float* out = (float*)d_out;

    char* ws = (char*)d_ws;
    size_t off = 0;
    auto alloc = [&](size_t bytes) -> void* {
        void* p = ws + off;
        off += (bytes + 255) & ~(size_t)255;
        return p;
    };
    ushort_t* bufH_b  = (ushort_t*)alloc((size_t)N * HC * 2);
    ushort_t* cat01_b = (ushort_t*)alloc((size_t)N * 768 * 2 + 2048);
    ushort_t* xres_b  = (ushort_t*)alloc((size_t)N * HC * 2);
    ushort_t* cat2_b  = (ushort_t*)alloc((size_t)N * 128 * 2);
    float*    bufRes  = (float*)alloc((size_t)N * C * 4);
    ushort_t* xb      = (ushort_t*)alloc((size_t)N * IND * 2);
    ushort_t* wBig    = (ushort_t*)alloc((size_t)WBIG * 2);
    ushort_t* wC1     = (ushort_t*)alloc((size_t)WC1 * 2);
    ushort_t* wC2     = (ushort_t*)alloc((size_t)WC2 * 2);
    float*    bBig    = (float*)alloc((size_t)1152 * 4);
    float*    bC1     = (float*)alloc((size_t)768 * 4);
    float*    bC2     = (float*)alloc((size_t)192 * 4);
    int*      counts  = (int*)alloc((size_t)N * 4);
    int*      cursor  = (int*)alloc((size_t)N * 4);
    int*      offsets = (int*)alloc((size_t)(N + 1) * 4);
    int*      srcs    = (int*)alloc((size_t)(EN + 8) * 4);   // s<<8 byte offsets + pad
    int*      blockSums = (int*)alloc((size_t)512 * 4);
    int*      blockBase = (int*)alloc((size_t)512 * 4);
    float*    pooled  = (float*)alloc((size_t)NG * C * 4);

    // ---- fused preprocessing (replaces zero_init+count+scan+fill+prep = 5 launches) ----
    {
        void* kp[] = {
            (void*)&x, (void*)&inp_w,
            (void*)&l0_wl, (void*)&l0_wr,
            (void*)&l1_wl, (void*)&l1_wr,
            (void*)&l2_wl, (void*)&l2_wr,
            (void*)&res_w,
            (void*)&inp_b,
            (void*)&l0_bl, (void*)&l0_br,
            (void*)&l1_bl, (void*)&l1_br,
            (void*)&l2_bl, (void*)&l2_br,
            (void*)&ei,
            (void*)&wBig, (void*)&wC1, (void*)&wC2, (void*)&xb,
            (void*)&bBig, (void*)&bC1, (void*)&bC2,
            (void*)&counts, (void*)&offsets, (void*)&cursor, (void*)&srcs,
            (void*)&blockSums, (void*)&blockBase
        };
        hipLaunchCooperativeKernel((const void*)pre_kernel, dim3(512), dim3(256),
                                   kp, 0, stream);
    }

    int mtiles256 = (N + 255) / 256;   // 79
    int mtiles = (N + 127) / 128;      // 157
    dim3 gblk(128);
    int gatBlocks = (N * 64 + 127) / 128;

    // fused: [x_res | l0_xl | l0_xr] = xb @ wBig (bf16 out; split at 384). 9 col-tiles = 3y x NT3
    gemm_mfma2<<<dim3(mtiles256, 3), dim3(512), 0, stream>>>(xb, wBig, bBig,
        xres_b, HC, cat01_b, 768, 384, N, 1152, IND, 3);
    gat6_kernel<<<gatBlocks, gblk, 0, stream>>>(cat01_b, l0_att, l0_bias,
                                                xres_b, bufH_b, offsets, srcs, N);
    // layer 1: [l1_xl | l1_xr] = h0 @ wC1. 6 col-tiles = 3y x NT2
    gemm_mfma2<<<dim3(mtiles256, 3), dim3(512), 0, stream>>>(bufH_b, wC1, bC1,
        nullptr, 0, cat01_b, 768, 0, N, 768, HC, 2);
    gat6_kernel<<<gatBlocks, gblk, 0, stream>>>(cat01_b, l1_att, l1_bias,
                                                bufH_b, bufH_b, offsets, srcs, N);
    // fused: [res | l2_xl | l2_xr] = h1 @ wC2 (res fp32, rest bf16) — small, keep 128-tile
    gemm_mfma<<<dim3(mtiles, 2), dim3(256), 0, stream>>>(bufH_b, wC2, bC2,
        bufRes, nullptr, C, cat2_b, 128, 64, N, 192, HC);
    gat1_kernel<<<gatBlocks, gblk, 0, stream>>>(cat2_b, l2_att, l2_bias,
                                                bufRes, out, offsets, srcs, N);
    // pooling + head
    pool_kernel<<<NG, 256, 0, stream>>>(out, batch, pooled, N);
    head_kernel<<<1, 256, 0, stream>>>(pooled, d1_w, d1_b, bn_g, bn_b, bn_m, bn_v,
                                       d2_w, d2_b, out + (size_t)N * C);
}

// Round 7
// 402.568 us; speedup vs baseline: 1.8697x; 1.8697x over previous
//
#include <hip/hip_runtime.h>
#include <hip/hip_bf16.h>
#include <math.h>

#define NN 20000
#define EE 320000
#define IND 128
#define HH 6
#define CC 64
#define HCC 384
#define NCC 16
#define NGG 64

typedef __bf16 bf16x8 __attribute__((ext_vector_type(8)));
typedef float f32x4 __attribute__((ext_vector_type(4)));
typedef float f32x2 __attribute__((ext_vector_type(2)));
typedef unsigned short ushort_t;
typedef unsigned int uint_t;

#define LOG2E 1.44269504088896f

__device__ inline ushort_t f2bf(float f) {
    union { float f; uint_t u; } x; x.f = f;
    uint_t r = (x.u + 0x7FFF + ((x.u >> 16) & 1)) >> 16;
    return (ushort_t)r;
}
// 8 packed bf16 (uint4) -> 4 f32x2 (pairs) for packed-f32 VALU
__device__ inline void bf8cvt2(uint4 v, f32x2* f) {
    union { uint_t u; float x; } a, b;
    a.u = v.x << 16; b.u = v.x & 0xFFFF0000u; f[0] = (f32x2){a.x, b.x};
    a.u = v.y << 16; b.u = v.y & 0xFFFF0000u; f[1] = (f32x2){a.x, b.x};
    a.u = v.z << 16; b.u = v.z & 0xFFFF0000u; f[2] = (f32x2){a.x, b.x};
    a.u = v.w << 16; b.u = v.w & 0xFFFF0000u; f[3] = (f32x2){a.x, b.x};
}

// DPP cross-lane add (VALU, no DS pipe). CTRL: 0xB1=xor1, 0x4E=xor2,
// 0x141=row_half_mirror (==xor4 once quad-uniform), 0x140=row_mirror (==xor8).
template <int CTRL>
__device__ inline float dppadd(float x) {
    int y = __builtin_amdgcn_mov_dpp(__builtin_bit_cast(int, x), CTRL, 0xF, 0xF, true);
    return x + __builtin_bit_cast(float, y);
}

// async global->LDS: lane L writes lds+16*L
__device__ inline void load_lds16(const ushort_t* g, ushort_t* l) {
    __builtin_amdgcn_global_load_lds(
        (const __attribute__((address_space(1))) void*)g,
        (__attribute__((address_space(3))) void*)l, 16, 0, 0);
}

// bijective XCD swizzle (m204): consecutive logical ids land on the SAME XCD.
// lin = HW launch order (lin%8 -> XCD). Returns logical tile id.
__device__ inline int xcd_swz(int lin, int nwg) {
    int q = nwg >> 3, r = nwg & 7;
    int xc = lin & 7, j = lin >> 3;
    return (xc < r ? xc * (q + 1) : r * (q + 1) + (xc - r) * q) + j;
}

// ---------------- utility kernels ----------------

__global__ void zero_init_kernel(int* counts, int* s6_tail, int* s1_tail,
                                 float* pooled, int n, int np) {
    int t = blockIdx.x * blockDim.x + threadIdx.x;
    if (t < n) counts[t] = 0;
    if (t < np) pooled[t] = 0.0f;
    if (t < 8) { s6_tail[t] = 0; s1_tail[t] = 0; }
}

__global__ void count_kernel(const int* __restrict__ ei, int* __restrict__ counts, int E) {
    int t = blockIdx.x * blockDim.x + threadIdx.x;
    if (t < E) atomicAdd(&counts[ei[E + t]], 1);
}

// exclusive scan of (counts[i]+1) -> offsets/cursor. LDS-staged, coalesced.
__global__ __launch_bounds__(1024) void scan_kernel(
    const int* __restrict__ counts, int* __restrict__ offsets,
    int* __restrict__ cursor, int n) {
    __shared__ int buf[NN];      // 80 KB
    __shared__ int part[1024];
    int t = threadIdx.x;
    for (int idx = t; idx < n; idx += 1024) buf[idx] = counts[idx] + 1;
    __syncthreads();
    int per = (n + 1023) / 1024;
    int base = t * per;
    int sum = 0;
    for (int j = 0; j < per; ++j) {
        int idx = base + j;
        if (idx < n) sum += buf[idx];
    }
    part[t] = sum;
    __syncthreads();
    for (int off = 1; off < 1024; off <<= 1) {
        int v = (t >= off) ? part[t - off] : 0;
        __syncthreads();
        part[t] += v;
        __syncthreads();
    }
    int run = (t == 0) ? 0 : part[t - 1];
    for (int j = 0; j < per; ++j) {
        int idx = base + j;
        if (idx < n) {
            int deg = buf[idx];
            buf[idx] = run;
            run += deg;
        }
    }
    __syncthreads();
    for (int idx = t; idx < n; idx += 1024) {
        int v = buf[idx];
        offsets[idx] = v;
        cursor[idx] = v;
    }
    if (t == 1023) offsets[n] = run;
}

// fill: store PRE-SCALED BYTE offsets (src*1536 for 768-short rows, src*256 for
// 128-short rows) -> kills the per-gather v_mul in gat kernels.
__global__ void fill_kernel(const int* __restrict__ ei, int* __restrict__ cursor,
                            int* __restrict__ srcs6, int* __restrict__ srcs1,
                            int E, int n) {
    int t = blockIdx.x * blockDim.x + threadIdx.x;
    if (t < E) {
        int s = ei[t];
        int d = ei[E + t];
        int slot = atomicAdd(&cursor[d], 1);
        srcs6[slot] = s * 1536;
        srcs1[slot] = s << 8;
    } else if (t < E + n) {
        int i = t - E;
        int slot = atomicAdd(&cursor[i], 1);
        srcs6[slot] = i * 1536;
        srcs1[slot] = i << 8;
    }
}

// ---------------- weight/input prep: fp32 -> bf16 TRANSPOSED ([N][K]) ----------------
#define WBIG (1152 * IND)
#define WC1 (768 * HCC)
#define WC2 (192 * HCC)
#define XB_N (NN * IND)
#define PREP_TOTAL (WBIG + WC1 + WC2 + XB_N + 1152 + 768 + 192)

__global__ void prep_kernel(const float* __restrict__ x, const float* __restrict__ inp_w,
    const float* __restrict__ l0wl, const float* __restrict__ l0wr,
    const float* __restrict__ l1wl, const float* __restrict__ l1wr,
    const float* __restrict__ l2wl, const float* __restrict__ l2wr,
    const float* __restrict__ resw,
    const float* __restrict__ inp_b,
    const float* __restrict__ l0bl, const float* __restrict__ l0br,
    const float* __restrict__ l1bl, const float* __restrict__ l1br,
    const float* __restrict__ l2bl, const float* __restrict__ l2br,
    ushort_t* wBig, ushort_t* wC1, ushort_t* wC2, ushort_t* xb,
    float* bBig, float* bC1, float* bC2)
{
    int i = blockIdx.x * blockDim.x + threadIdx.x;
    if (i >= PREP_TOTAL) return;
    if (i < WBIG) {
        int col = i >> 7, k = i & 127;
        float v;
        if (col < 384)      v = inp_w[k * 384 + col];
        else if (col < 768) v = l0wl[k * 384 + (col - 384)];
        else                v = l0wr[k * 384 + (col - 768)];
        wBig[i] = f2bf(v); return;
    }
    i -= WBIG;
    if (i < WC1) {
        int col = i / 384, k = i - col * 384;
        float v = col < 384 ? l1wl[k * 384 + col] : l1wr[k * 384 + (col - 384)];
        wC1[i] = f2bf(v); return;
    }
    i -= WC1;
    if (i < WC2) {
        int col = i / 384, k = i - col * 384;
        float v;
        if (col < 64)       v = resw[k * 64 + col];
        else if (col < 128) v = l2wl[k * 64 + (col - 64)];
        else                v = l2wr[k * 64 + (col - 128)];
        wC2[i] = f2bf(v); return;
    }
    i -= WC2;
    if (i < XB_N) { xb[i] = f2bf(x[i]); return; }
    i -= XB_N;
    if (i < 1152) {
        float v;
        if (i < 384)      v = inp_b[i];
        else if (i < 768) v = l0bl[i - 384];
        else              v = l0br[i - 768];
        bBig[i] = v; return;
    }
    i -= 1152;
    if (i < 768) { bC1[i] = i < 384 ? l1bl[i] : l1br[i - 384]; return; }
    i -= 768;
    if (i < 192) {
        float v;
        if (i < 64)       v = 0.0f;
        else if (i < 128) v = l2bl[i - 64];
        else              v = l2br[i - 128];
        bC2[i] = v; return;
    }
}

// ---------------- bf16 MFMA GEMM (big): M-tile 256, 8 waves, col-tile loop, XCD swizzle ----
__global__ __launch_bounds__(512) void gemm_mfma2(
    const ushort_t* __restrict__ A, const ushort_t* __restrict__ BT,
    const float* __restrict__ bias,
    ushort_t* __restrict__ Cb1, int ld1,
    ushort_t* __restrict__ Cb2, int ld2, int split,
    int M, int N, int K, int NT)
{
    __shared__ ushort_t Bs[2][2][128 * 32];   // 32 KB
    int t = threadIdx.x;
    int w = t >> 6, L = t & 63;               // w in [0,8)
    // XCD swizzle: consecutive logical tiles (m-fastest) share an XCD's L2 -> B panel reuse
    int nwg = gridDim.x * gridDim.y;
    int logical = xcd_swz(blockIdx.y * gridDim.x + blockIdx.x, nwg);
    int bx = logical % gridDim.x;
    int by = logical / gridDim.x;
    int m0 = bx * 256;
    int q = L >> 4, r16 = L & 15;
    int lr = L >> 2;
    int lc = ((L & 3) ^ ((lr >> 1) & 3)) * 8;   // pre-swizzled source chunk
    int sw = (q ^ ((r16 >> 1) & 3)) * 8;        // matching ds_read swizzle
    int oB = (w * 16) * 32;                     // wave stages B rows [w*16, w*16+16)

    int rA0 = min(m0 + w * 32 + r16, M - 1);
    int rA1 = min(m0 + w * 32 + 16 + r16, M - 1);
    const ushort_t* pA0base = A + (size_t)rA0 * K + q * 8;
    const ushort_t* pA1base = A + (size_t)rA1 * K + q * 8;

    for (int nt = 0; nt < NT; ++nt) {
        int n0 = (by * NT + nt) * 128;
        int rB = min(n0 + w * 16 + lr, N - 1);
        const ushort_t* gB = BT + (size_t)rB * K + lc;
        const ushort_t* pA0 = pA0base;
        const ushort_t* pA1 = pA1base;

        f32x4 acc[2][8];
#pragma unroll
        for (int a = 0; a < 2; ++a)
#pragma unroll
            for (int b = 0; b < 8; ++b) acc[a][b] = (f32x4){0.f, 0.f, 0.f, 0.f};

        load_lds16(gB, &Bs[0][0][oB]);
        load_lds16(gB + 32, &Bs[0][1][oB]);
        gB += 64;
        bf16x8 a0 = *(const bf16x8*)pA0;
        bf16x8 a2 = *(const bf16x8*)(pA0 + 32);
        bf16x8 a1 = *(const bf16x8*)pA1;
        bf16x8 a3 = *(const bf16x8*)(pA1 + 32);
        pA0 += 64; pA1 += 64;

        int buf = 0;
        for (int k0 = 0; k0 < K; k0 += 64) {
            __syncthreads();
            bool more = (k0 + 64 < K);
            if (more) {
                int nb = buf ^ 1;
                load_lds16(gB, &Bs[nb][0][oB]);
                load_lds16(gB + 32, &Bs[nb][1][oB]);
                gB += 64;
            }
            bf16x8 na0, na1, na2, na3;
            if (more) {
                na0 = *(const bf16x8*)pA0;
                na2 = *(const bf16x8*)(pA0 + 32);
                na1 = *(const bf16x8*)pA1;
                na3 = *(const bf16x8*)(pA1 + 32);
                pA0 += 64; pA1 += 64;
            }
#pragma unroll
            for (int ct = 0; ct < 8; ++ct) {
                bf16x8 blo = *(const bf16x8*)&Bs[buf][0][(ct * 16 + r16) * 32 + sw];
                bf16x8 bhi = *(const bf16x8*)&Bs[buf][1][(ct * 16 + r16) * 32 + sw];
                acc[0][ct] = __builtin_amdgcn_mfma_f32_16x16x32_bf16(blo, a0, acc[0][ct], 0, 0, 0);
                acc[1][ct] = __builtin_amdgcn_mfma_f32_16x16x32_bf16(blo, a1, acc[1][ct], 0, 0, 0);
                acc[0][ct] = __builtin_amdgcn_mfma_f32_16x16x32_bf16(bhi, a2, acc[0][ct], 0, 0, 0);
                acc[1][ct] = __builtin_amdgcn_mfma_f32_16x16x32_bf16(bhi, a3, acc[1][ct], 0, 0, 0);
            }
            if (more) { a0 = na0; a1 = na1; a2 = na2; a3 = na3; }
            buf ^= 1;
        }
#pragma unroll
        for (int rt = 0; rt < 2; ++rt) {
            int row = m0 + w * 32 + rt * 16 + r16;
            if (row >= M) continue;
#pragma unroll
            for (int ct = 0; ct < 8; ++ct) {
                int colb = n0 + ct * 16 + q * 4;
                if (colb >= N) continue;
                float4 bv = *(const float4*)(bias + colb);
                uint2 pk;
                pk.x = (uint_t)f2bf(acc[rt][ct][0] + bv.x) | ((uint_t)f2bf(acc[rt][ct][1] + bv.y) << 16);
                pk.y = (uint_t)f2bf(acc[rt][ct][2] + bv.z) | ((uint_t)f2bf(acc[rt][ct][3] + bv.w) << 16);
                if (colb < split)
                    *(uint2*)(Cb1 + (size_t)row * ld1 + colb) = pk;
                else
                    *(uint2*)(Cb2 + (size_t)row * ld2 + (colb - split)) = pk;
            }
        }
    }
}

// ---------------- bf16 MFMA GEMM (small, 128-tile): kept for gemm3, XCD swizzle ----------------
__global__ __launch_bounds__(256) void gemm_mfma(
    const ushort_t* __restrict__ A, const ushort_t* __restrict__ BT,
    const float* __restrict__ bias,
    float* __restrict__ Cf, ushort_t* __restrict__ Cb1, int ld1,
    ushort_t* __restrict__ Cb2, int ld2, int split,
    int M, int N, int K)
{
    __shared__ ushort_t Bs[2][2][128 * 32];
    int t = threadIdx.x;
    int w = t >> 6, L = t & 63;
    int nwg = gridDim.x * gridDim.y;
    int logical = xcd_swz(blockIdx.y * gridDim.x + blockIdx.x, nwg);
    int m0 = (logical % gridDim.x) * 128;
    int n0 = (logical / gridDim.x) * 128;
    int q = L >> 4, r16 = L & 15;

    f32x4 acc[2][8];
#pragma unroll
    for (int a = 0; a < 2; ++a)
#pragma unroll
        for (int b = 0; b < 8; ++b) acc[a][b] = (f32x4){0.f, 0.f, 0.f, 0.f};

    int lr = L >> 2;
    int lc = ((L & 3) ^ ((lr >> 1) & 3)) * 8;
    int rB0 = min(n0 + w * 32 + lr, N - 1);
    int rB1 = min(n0 + w * 32 + 16 + lr, N - 1);
    const ushort_t* gB0 = BT + (size_t)rB0 * K + lc;
    const ushort_t* gB1 = BT + (size_t)rB1 * K + lc;
    int oB0 = (w * 32) * 32;
    int oB1 = (w * 32 + 16) * 32;

    int rA0 = min(m0 + w * 32 + r16, M - 1);
    int rA1 = min(m0 + w * 32 + 16 + r16, M - 1);
    const ushort_t* pA0 = A + (size_t)rA0 * K + q * 8;
    const ushort_t* pA1 = A + (size_t)rA1 * K + q * 8;

    int sw = (q ^ ((r16 >> 1) & 3)) * 8;

    load_lds16(gB0, &Bs[0][0][oB0]);
    load_lds16(gB1, &Bs[0][0][oB1]);
    load_lds16(gB0 + 32, &Bs[0][1][oB0]);
    load_lds16(gB1 + 32, &Bs[0][1][oB1]);
    gB0 += 64; gB1 += 64;
    bf16x8 a0 = *(const bf16x8*)pA0;
    bf16x8 a2 = *(const bf16x8*)(pA0 + 32);
    bf16x8 a1 = *(const bf16x8*)pA1;
    bf16x8 a3 = *(const bf16x8*)(pA1 + 32);
    pA0 += 64; pA1 += 64;

    int buf = 0;
    for (int k0 = 0; k0 < K; k0 += 64) {
        __syncthreads();
        bool more = (k0 + 64 < K);
        if (more) {
            int nb = buf ^ 1;
            load_lds16(gB0, &Bs[nb][0][oB0]);
            load_lds16(gB1, &Bs[nb][0][oB1]);
            load_lds16(gB0 + 32, &Bs[nb][1][oB0]);
            load_lds16(gB1 + 32, &Bs[nb][1][oB1]);
            gB0 += 64; gB1 += 64;
        }
        bf16x8 na0, na1, na2, na3;
        if (more) {
            na0 = *(const bf16x8*)pA0;
            na2 = *(const bf16x8*)(pA0 + 32);
            na1 = *(const bf16x8*)pA1;
            na3 = *(const bf16x8*)(pA1 + 32);
            pA0 += 64; pA1 += 64;
        }
#pragma unroll
        for (int ct = 0; ct < 8; ++ct) {
            bf16x8 blo = *(const bf16x8*)&Bs[buf][0][(ct * 16 + r16) * 32 + sw];
            bf16x8 bhi = *(const bf16x8*)&Bs[buf][1][(ct * 16 + r16) * 32 + sw];
            acc[0][ct] = __builtin_amdgcn_mfma_f32_16x16x32_bf16(blo, a0, acc[0][ct], 0, 0, 0);
            acc[1][ct] = __builtin_amdgcn_mfma_f32_16x16x32_bf16(blo, a1, acc[1][ct], 0, 0, 0);
            acc[0][ct] = __builtin_amdgcn_mfma_f32_16x16x32_bf16(bhi, a2, acc[0][ct], 0, 0, 0);
            acc[1][ct] = __builtin_amdgcn_mfma_f32_16x16x32_bf16(bhi, a3, acc[1][ct], 0, 0, 0);
        }
        if (more) { a0 = na0; a1 = na1; a2 = na2; a3 = na3; }
        buf ^= 1;
    }
#pragma unroll
    for (int rt = 0; rt < 2; ++rt) {
        int row = m0 + w * 32 + rt * 16 + r16;
        if (row >= M) continue;
#pragma unroll
        for (int ct = 0; ct < 8; ++ct) {
            int colb = n0 + ct * 16 + q * 4;
            if (colb >= N) continue;
            float4 bv = *(const float4*)(bias + colb);
            float v0 = acc[rt][ct][0] + bv.x;
            float v1 = acc[rt][ct][1] + bv.y;
            float v2 = acc[rt][ct][2] + bv.z;
            float v3 = acc[rt][ct][3] + bv.w;
            if (colb < split) {
                if (Cf) {
                    *(float4*)(Cf + (size_t)row * ld1 + colb) = make_float4(v0, v1, v2, v3);
                } else {
                    uint2 pk;
                    pk.x = (uint_t)f2bf(v0) | ((uint_t)f2bf(v1) << 16);
                    pk.y = (uint_t)f2bf(v2) | ((uint_t)f2bf(v3) << 16);
                    *(uint2*)(Cb1 + (size_t)row * ld1 + colb) = pk;
                }
            } else {
                uint2 pk;
                pk.x = (uint_t)f2bf(v0) | ((uint_t)f2bf(v1) << 16);
                pk.y = (uint_t)f2bf(v2) | ((uint_t)f2bf(v3) << 16);
                *(uint2*)(Cb2 + (size_t)row * ld2 + (colb - split)) = pk;
            }
        }
    }
}

// ---------------- GATv2 H=6: branchless 1-deep pair loop, byte-offset srcs ----------------
__global__ __launch_bounds__(128) void gat6_kernel(
    const ushort_t* __restrict__ cat, const float* __restrict__ att,
    const float* __restrict__ bias, const ushort_t* __restrict__ resB,
    ushort_t* __restrict__ outB,
    const int* __restrict__ offsets, const int* __restrict__ srcs6, int n)
{
    int wid = (blockIdx.x * blockDim.x + threadIdx.x) >> 6;
    if (wid >= n) return;
    int lane = threadIdx.x & 63;
    int h = lane >> 3, c8 = lane & 7;
    bool hv = h < HH;
    int off = h * 64 + c8 * 8;
    int offL2 = (hv ? off : off - 384) * 2;   // BYTE offset; invalid lanes alias groups 0/1
    int i = wid;
    int beg = __builtin_amdgcn_readfirstlane(offsets[i]);
    int end = __builtin_amdgcn_readfirstlane(offsets[i + 1]);
    int deg = end - beg;
    int P = (deg + 1) >> 1;
    const char* catc = (const char*)cat;

    f32x2 xr2[4], att2[4];
    {
        uint4 v = *(const uint4*)(catc + (size_t)i * 1536 + 768 + offL2);
        bf8cvt2(v, xr2);
    }
#pragma unroll
    for (int j = 0; j < 4; ++j) {
        int o = (offL2 >> 1) + 2 * j;
        att2[j] = (f32x2){att[o] * LOG2E, att[o + 1] * LOG2E};
    }

    float s = 0.0f;
    f32x2 acc2[4];
#pragma unroll
    for (int j = 0; j < 4; ++j) acc2[j] = (f32x2){0.f, 0.f};

    int bA0 = srcs6[beg], bB0 = srcs6[beg + 1];
    uint4 cA = *(const uint4*)(catc + (size_t)(uint_t)bA0 + offL2);
    uint4 cB = *(const uint4*)(catc + (size_t)(uint_t)bB0 + offL2);
    int iA1 = srcs6[beg + 2], iB1 = srcs6[beg + 3];

    for (int p = 0; p < P; ++p) {
        uint4 nA = cA, nB = cB;
        bool pre = (p + 1 < P);       // uniform branch: skip useless last prefetch
        if (pre) {
            nA = *(const uint4*)(catc + (size_t)(uint_t)iA1 + offL2);
            nB = *(const uint4*)(catc + (size_t)(uint_t)iB1 + offL2);
            iA1 = srcs6[beg + 2 * p + 4];
            iB1 = srcs6[beg + 2 * p + 5];
        }
        f32x2 xlA[4], xlB[4];
        bf8cvt2(cA, xlA);
        bf8cvt2(cB, xlB);
        f32x2 pA2 = (f32x2){0.f, 0.f}, pB2 = (f32x2){0.f, 0.f};
#pragma unroll
        for (int j = 0; j < 4; ++j) {
            f32x2 ta = xlA[j] + xr2[j];
            ta = __builtin_elementwise_max(ta, ta * 0.2f);
            pA2 += ta * att2[j];
            f32x2 tb = xlB[j] + xr2[j];
            tb = __builtin_elementwise_max(tb, tb * 0.2f);
            pB2 += tb * att2[j];
        }
        float pA = pA2.x + pA2.y, pB = pB2.x + pB2.y;
        pA = dppadd<0xB1>(pA);
        pB = dppadd<0xB1>(pB);
        pA = dppadd<0x4E>(pA);
        pB = dppadd<0x4E>(pB);
        pA = dppadd<0x141>(pA);
        pB = dppadd<0x141>(pB);
        float wA = __builtin_amdgcn_exp2f(pA);
        float wB = (2 * p + 1 < deg) ? __builtin_amdgcn_exp2f(pB) : 0.0f;
        s += wA + wB;
        f32x2 wA2 = (f32x2){wA, wA}, wB2 = (f32x2){wB, wB};
#pragma unroll
        for (int j = 0; j < 4; ++j) {
            acc2[j] += wA2 * xlA[j];
            acc2[j] += wB2 * xlB[j];
        }
        cA = nA; cB = nB;
    }

    if (hv) {
        float inv = 1.0f / (s + 1e-16f);
        size_t ob = (size_t)i * HCC + off;
        uint4 rv = *(const uint4*)(resB + ob);
        f32x2 rr[4];
        bf8cvt2(rv, rr);
        ushort_t u[8];
#pragma unroll
        for (int j = 0; j < 4; ++j) {
            float v0 = acc2[j].x * inv + bias[off + 2 * j];
            float v1 = acc2[j].y * inv + bias[off + 2 * j + 1];
            v0 = v0 > 0.0f ? v0 : expm1f(v0);
            v1 = v1 > 0.0f ? v1 : expm1f(v1);
            u[2 * j]     = f2bf(v0 + rr[j].x);
            u[2 * j + 1] = f2bf(v1 + rr[j].y);
        }
        *(uint4*)(outB + ob) = *(uint4*)u;
    }
}

// ---------------- GATv2 H=1: single-pass exp2-folded, DPP reduce, byte-offset srcs ----------------
__global__ __launch_bounds__(128) void gat1_kernel(
    const ushort_t* __restrict__ cat, const float* __restrict__ att,
    const float* __restrict__ bias, const float* __restrict__ res,
    float* __restrict__ out,
    const int* __restrict__ offsets, const int* __restrict__ srcs1, int n)
{
    int wid = (blockIdx.x * blockDim.x + threadIdx.x) >> 6;
    if (wid >= n) return;
    int lane = threadIdx.x & 63;
    int e8 = lane >> 3, c8 = lane & 7;
    int i = wid;
    int beg = __builtin_amdgcn_readfirstlane(offsets[i]);
    int end = __builtin_amdgcn_readfirstlane(offsets[i + 1]);
    const char* catc = (const char*)cat;

    f32x2 xr2[4], att2[4];
    {
        uint4 v = *(const uint4*)(cat + (size_t)i * 128 + 64 + c8 * 8);
        bf8cvt2(v, xr2);
    }
#pragma unroll
    for (int j = 0; j < 4; ++j)
        att2[j] = (f32x2){att[c8 * 8 + 2 * j] * LOG2E, att[c8 * 8 + 2 * j + 1] * LOG2E};

    float s = 0.0f;
    f32x2 acc2[4];
#pragma unroll
    for (int j = 0; j < 4; ++j) acc2[j] = (f32x2){0.f, 0.f};

    const uint4 z = make_uint4(0u, 0u, 0u, 0u);
    int p = beg + e8;
    bool val = p < end;
    int b = val ? srcs1[p] : (i << 8);
    uint4 v = *(const uint4*)(catc + (size_t)(uint_t)b + c8 * 16);

    for (int p0 = beg; p0 < end; p0 += 8) {
        uint4 nv = z;
        bool nval = false;
        if (p0 + 8 < end) {
            int np = p0 + 8 + e8;
            nval = np < end;
            int nb = nval ? srcs1[np] : (i << 8);
            nv = *(const uint4*)(catc + (size_t)(uint_t)nb + c8 * 16);
        }
        f32x2 xl[4];
        bf8cvt2(v, xl);
        f32x2 pp2 = (f32x2){0.f, 0.f};
#pragma unroll
        for (int j = 0; j < 4; ++j) {
            f32x2 tv = xl[j] + xr2[j];
            tv = __builtin_elementwise_max(tv, tv * 0.2f);
            pp2 += tv * att2[j];
        }
        float partial = pp2.x + pp2.y;
        partial = dppadd<0xB1>(partial);
        partial = dppadd<0x4E>(partial);
        partial = dppadd<0x141>(partial);
        float wE = val ? __builtin_amdgcn_exp2f(partial) : 0.0f;
        s += wE;
        f32x2 w2 = (f32x2){wE, wE};
#pragma unroll
        for (int j = 0; j < 4; ++j) acc2[j] += w2 * xl[j];
        v = nv;
        val = nval;
    }

    s = dppadd<0x140>(s);
    s += __shfl_xor(s, 16, 64);
    s += __shfl_xor(s, 32, 64);
#pragma unroll
    for (int j = 0; j < 4; ++j) {
        acc2[j].x += __shfl_xor(acc2[j].x, 8, 64);
        acc2[j].y += __shfl_xor(acc2[j].y, 8, 64);
        acc2[j].x += __shfl_xor(acc2[j].x, 16, 64);
        acc2[j].y += __shfl_xor(acc2[j].y, 16, 64);
        acc2[j].x += __shfl_xor(acc2[j].x, 32, 64);
        acc2[j].y += __shfl_xor(acc2[j].y, 32, 64);
    }
    if (e8 == 0) {
        float inv = 1.0f / (s + 1e-16f);
        size_t ob = (size_t)i * CC + c8 * 8;
        float4 r0 = *(const float4*)(res + ob);
        float4 r1 = *(const float4*)(res + ob + 4);
        float rr[8] = {r0.x, r0.y, r0.z, r0.w, r1.x, r1.y, r1.z, r1.w};
        float av[8] = {acc2[0].x, acc2[0].y, acc2[1].x, acc2[1].y,
                       acc2[2].x, acc2[2].y, acc2[3].x, acc2[3].y};
#pragma unroll
        for (int j = 0; j < 8; ++j) {
            float v2 = av[j] * inv + bias[c8 * 8 + j];
            v2 = v2 > 0.0f ? v2 : expm1f(v2);
            av[j] = v2 + rr[j];
        }
        *(float4*)(out + ob) = make_float4(av[0], av[1], av[2], av[3]);
        *(float4*)(out + ob + 4) = make_float4(av[4], av[5], av[6], av[7]);
    }
}

// ---------------- pooling: 4 blocks per group (batch sorted), one atomic per block ----------------
__global__ __launch_bounds__(256) void pool_kernel(const float* __restrict__ h,
                                                   const int* __restrict__ batch,
                                                   float* __restrict__ pooled, int n) {
    int b = blockIdx.x;            // NG*4 blocks
    int g = b >> 2, qd = b & 3;
    int t = threadIdx.x;           // 256
    int w = t >> 6, lane = t & 63;
    int lo = 0, hi = n;
    while (lo < hi) { int mid = (lo + hi) >> 1; if (batch[mid] < g) lo = mid + 1; else hi = mid; }
    int start = lo;
    int hi2 = n;
    while (lo < hi2) { int mid = (lo + hi2) >> 1; if (batch[mid] < g + 1) lo = mid + 1; else hi2 = mid; }
    int endd = lo;
    int len = endd - start;
    int q0 = start + (len * qd) / 4;
    int q1 = start + (len * (qd + 1)) / 4;
    float acc = 0.0f;
    for (int r = q0 + w; r < q1; r += 4)
        acc += h[(size_t)r * 64 + lane];
    __shared__ float red[4][64];
    red[w][lane] = acc;
    __syncthreads();
    if (w == 0) {
        float v2 = red[0][lane] + red[1][lane] + red[2][lane] + red[3][lane];
        atomicAdd(&pooled[g * 64 + lane], v2);
    }
}

// ---------------- dense head: LDS-staged operands (was scalar-global latency-bound) ----------------
__global__ __launch_bounds__(256) void head_kernel(const float* __restrict__ pooled,
                            const float* __restrict__ d1w, const float* __restrict__ d1b,
                            const float* __restrict__ bng, const float* __restrict__ bnb,
                            const float* __restrict__ bnm, const float* __restrict__ bnv,
                            const float* __restrict__ d2w, const float* __restrict__ d2b,
                            float* __restrict__ zout) {
    __shared__ float pl[64 * 64];   // 16 KB
    __shared__ float w1[64 * 64];   // 16 KB
    __shared__ float w2[64 * NCC];  // 4 KB
    __shared__ float z1[64 * 64];   // 16 KB
    int t = threadIdx.x;  // 256
    for (int i = t * 4; i < 64 * 64; i += 1024) {
        *(float4*)&pl[i] = *(const float4*)&pooled[i];
        *(float4*)&w1[i] = *(const float4*)&d1w[i];
    }
    for (int i = t * 4; i < 64 * NCC; i += 1024)
        *(float4*)&w2[i] = *(const float4*)&d2w[i];
    __syncthreads();
    for (int idx = t; idx < 64 * 64; idx += 256) {
        int r = idx >> 6, c = idx & 63;
        float acc = d1b[c];
        for (int k = 0; k < 64; ++k) acc += pl[r * 64 + k] * w1[k * 64 + c];
        acc = (acc - bnm[c]) / sqrtf(bnv[c] + 1e-5f) * bng[c] + bnb[c];
        z1[idx] = acc > 0.0f ? acc : 0.0f;
    }
    __syncthreads();
    for (int idx = t; idx < 64 * NCC; idx += 256) {
        int r = idx >> 4, c = idx & 15;
        float acc = d2b[c];
        for (int k = 0; k < 64; ++k) acc += z1[r * 64 + k] * w2[k * NCC + c];
        zout[idx] = acc;
    }
}

// ---------------- launcher ----------------

extern "C" void kernel_launch(void* const* d_in, const int* in_sizes, int n_in,
                              void* d_out, int out_size, void* d_ws, size_t ws_size,
                              hipStream_t stream) {
    const int N = NN, E = EE, C = CC, HC = HCC, NG = NGG;
    const int EN = E + N;

    const float* x     = (const float*)d_in[0];
    const int*   ei    = (const int*)d_in[1];
    const int*   batch = (const int*)d_in[2];
    const float* inp_w = (const float*)d_in[3];
    const float* inp_b = (const float*)d_in[4];
    const float* l0_wl = (const float*)d_in[5];
    const float* l0_bl = (const float*)d_in[6];
    const float* l0_wr = (const float*)d_in[7];
    const float* l0_br = (const float*)d_in[8];
    const float* l0_att = (const float*)d_in[9];
    const float* l0_bias = (const float*)d_in[10];
    const float* l1_wl = (const float*)d_in[11];
    const float* l1_bl = (const float*)d_in[12];
    const float* l1_wr = (const float*)d_in[13];
    const float* l1_br = (const float*)d_in[14];
    const float* l1_att = (const float*)d_in[15];
    const float* l1_bias = (const float*)d_in[16];
    const float* l2_wl = (const float*)d_in[17];
    const float* l2_bl = (const float*)d_in[18];
    const float* l2_wr = (const float*)d_in[19];
    const float* l2_br = (const float*)d_in[20];
    const float* l2_att = (const float*)d_in[21];
    const float* l2_bias = (const float*)d_in[22];
    const float* res_w = (const float*)d_in[23];
    const float* d1_w = (const float*)d_in[24];
    const float* d1_b = (const float*)d_in[25];
    const float* bn_g = (const float*)d_in[26];
    const float* bn_b = (const float*)d_in[27];
    const float* bn_m = (const float*)d_in[28];
    const float* bn_v = (const float*)d_in[29];
    const float* d2_w = (const float*)d_in[30];
    const float* d2_b = (const float*)d_in[31];

    float* out = (float*)d_out;

    char* ws = (char*)d_ws;
    size_t off = 0;
    auto alloc = [&](size_t bytes) -> void* {
        void* p = ws + off;
        off += (bytes + 255) & ~(size_t)255;
        return p;
    };
    ushort_t* bufH_b  = (ushort_t*)alloc((size_t)N * HC * 2);
    ushort_t* cat01_b = (ushort_t*)alloc((size_t)N * 768 * 2 + 2048);
    ushort_t* xres_b  = (ushort_t*)alloc((size_t)N * HC * 2);
    ushort_t* cat2_b  = (ushort_t*)alloc((size_t)N * 128 * 2);
    float*    bufRes  = (float*)alloc((size_t)N * C * 4);
    ushort_t* xb      = (ushort_t*)alloc((size_t)N * IND * 2);
    ushort_t* wBig    = (ushort_t*)alloc((size_t)WBIG * 2);
    ushort_t* wC1     = (ushort_t*)alloc((size_t)WC1 * 2);
    ushort_t* wC2     = (ushort_t*)alloc((size_t)WC2 * 2);
    float*    bBig    = (float*)alloc((size_t)1152 * 4);
    float*    bC1     = (float*)alloc((size_t)768 * 4);
    float*    bC2     = (float*)alloc((size_t)192 * 4);
    int*      counts  = (int*)alloc((size_t)N * 4);
    int*      cursor  = (int*)alloc((size_t)N * 4);
    int*      offsets = (int*)alloc((size_t)(N + 1) * 4);
    int*      srcs6   = (int*)alloc((size_t)(EN + 8) * 4);   // byte offsets (x1536)
    int*      srcs1   = (int*)alloc((size_t)(EN + 8) * 4);   // byte offsets (x256)
    float*    pooled  = (float*)alloc((size_t)NG * C * 4);

    zero_init_kernel<<<(N + 255) / 256, 256, 0, stream>>>(counts, srcs6 + EN, srcs1 + EN,
                                                          pooled, N, NG * C);
    count_kernel<<<(E + 255) / 256, 256, 0, stream>>>(ei, counts, E);
    scan_kernel<<<1, 1024, 0, stream>>>(counts, offsets, cursor, N);
    fill_kernel<<<(EN + 255) / 256, 256, 0, stream>>>(ei, cursor, srcs6, srcs1, E, N);
    prep_kernel<<<(PREP_TOTAL + 255) / 256, 256, 0, stream>>>(
        x, inp_w, l0_wl, l0_wr, l1_wl, l1_wr, l2_wl, l2_wr, res_w,
        inp_b, l0_bl, l0_br, l1_bl, l1_br, l2_bl, l2_br,
        wBig, wC1, wC2, xb, bBig, bC1, bC2);

    int mtiles256 = (N + 255) / 256;   // 79
    int mtiles = (N + 127) / 128;      // 157
    dim3 gblk(128);
    int gatBlocks = (N * 64 + 127) / 128;

    // fused: [x_res | l0_xl | l0_xr] = xb @ wBig (bf16 out; split at 384). 9 col-tiles = 3y x NT3
    gemm_mfma2<<<dim3(mtiles256, 3), dim3(512), 0, stream>>>(xb, wBig, bBig,
        xres_b, HC, cat01_b, 768, 384, N, 1152, IND, 3);
    gat6_kernel<<<gatBlocks, gblk, 0, stream>>>(cat01_b, l0_att, l0_bias,
                                                xres_b, bufH_b, offsets, srcs6, N);
    // layer 1: [l1_xl | l1_xr] = h0 @ wC1. 6 col-tiles = 3y x NT2
    gemm_mfma2<<<dim3(mtiles256, 3), dim3(512), 0, stream>>>(bufH_b, wC1, bC1,
        nullptr, 0, cat01_b, 768, 0, N, 768, HC, 2);
    gat6_kernel<<<gatBlocks, gblk, 0, stream>>>(cat01_b, l1_att, l1_bias,
                                                bufH_b, bufH_b, offsets, srcs6, N);
    // fused: [res | l2_xl | l2_xr] = h1 @ wC2 (res fp32, rest bf16) — small, keep 128-tile
    gemm_mfma<<<dim3(mtiles, 2), dim3(256), 0, stream>>>(bufH_b, wC2, bC2,
        bufRes, nullptr, C, cat2_b, 128, 64, N, 192, HC);
    gat1_kernel<<<gatBlocks, gblk, 0, stream>>>(cat2_b, l2_att, l2_bias,
                                                bufRes, out, offsets, srcs1, N);
    // pooling + head
    pool_kernel<<<NG * 4, 256, 0, stream>>>(out, batch, pooled, N);
    head_kernel<<<1, 256, 0, stream>>>(pooled, d1_w, d1_b, bn_g, bn_b, bn_m, bn_v,
                                       d2_w, d2_b, out + (size_t)N * C);
}

// Round 8
// 394.202 us; speedup vs baseline: 1.9094x; 1.0212x over previous
//
#include <hip/hip_runtime.h>
#include <hip/hip_bf16.h>
#include <math.h>

#define NN 20000
#define EE 320000
#define IND 128
#define HH 6
#define CC 64
#define HCC 384
#define NCC 16
#define NGG 64

typedef __bf16 bf16x8 __attribute__((ext_vector_type(8)));
typedef float f32x4 __attribute__((ext_vector_type(4)));
typedef float f32x2 __attribute__((ext_vector_type(2)));
typedef unsigned short ushort_t;
typedef unsigned int uint_t;

#define LOG2E 1.44269504088896f

__device__ inline ushort_t f2bf(float f) {
    union { float f; uint_t u; } x; x.f = f;
    uint_t r = (x.u + 0x7FFF + ((x.u >> 16) & 1)) >> 16;
    return (ushort_t)r;
}
// 8 packed bf16 (uint4) -> 4 f32x2 (pairs) for packed-f32 VALU
__device__ inline void bf8cvt2(uint4 v, f32x2* f) {
    union { uint_t u; float x; } a, b;
    a.u = v.x << 16; b.u = v.x & 0xFFFF0000u; f[0] = (f32x2){a.x, b.x};
    a.u = v.y << 16; b.u = v.y & 0xFFFF0000u; f[1] = (f32x2){a.x, b.x};
    a.u = v.z << 16; b.u = v.z & 0xFFFF0000u; f[2] = (f32x2){a.x, b.x};
    a.u = v.w << 16; b.u = v.w & 0xFFFF0000u; f[3] = (f32x2){a.x, b.x};
}

// DPP cross-lane add (VALU, no DS pipe). CTRL: 0xB1=xor1, 0x4E=xor2,
// 0x141=row_half_mirror (==xor4 once quad-uniform), 0x140=row_mirror (==xor8).
template <int CTRL>
__device__ inline float dppadd(float x) {
    int y = __builtin_amdgcn_mov_dpp(__builtin_bit_cast(int, x), CTRL, 0xF, 0xF, true);
    return x + __builtin_bit_cast(float, y);
}

// async global->LDS: lane L writes lds+16*L
__device__ inline void load_lds16(const ushort_t* g, ushort_t* l) {
    __builtin_amdgcn_global_load_lds(
        (const __attribute__((address_space(1))) void*)g,
        (__attribute__((address_space(3))) void*)l, 16, 0, 0);
}

// bijective XCD swizzle (m204): consecutive logical ids land on the SAME XCD.
// lin = HW launch order (lin%8 -> XCD). Returns logical tile id.
__device__ inline int xcd_swz(int lin, int nwg) {
    int q = nwg >> 3, r = nwg & 7;
    int xc = lin & 7, j = lin >> 3;
    return (xc < r ? xc * (q + 1) : r * (q + 1) + (xc - r) * q) + j;
}

// ---------------- utility kernels ----------------

__global__ void zero_init_kernel(int* counts, int* srcs_tail,
                                 float* pooled, int n, int np) {
    int t = blockIdx.x * blockDim.x + threadIdx.x;
    if (t < n) counts[t] = 0;
    if (t < np) pooled[t] = 0.0f;
    if (t < 8) srcs_tail[t] = 0;
}

__global__ void count_kernel(const int* __restrict__ ei, int* __restrict__ counts, int E) {
    int t = blockIdx.x * blockDim.x + threadIdx.x;
    if (t < E) atomicAdd(&counts[ei[E + t]], 1);
}

// distributed scan (replaces r7's single-block scan = one CU serialized ~10-30us):
// phase 1: per-block exclusive scan of (counts+1), local result -> offsets (scratch),
//          block total -> blockSums. 79 parallel blocks.
__global__ __launch_bounds__(256) void scan_local_kernel(
    const int* __restrict__ counts, int* __restrict__ offsets,
    int* __restrict__ blockSums, int n) {
    __shared__ int lp[256];
    int t = threadIdx.x, b = blockIdx.x;
    int i = b * 256 + t;
    int v = (i < n) ? counts[i] + 1 : 0;
    lp[t] = v;
    __syncthreads();
    for (int o = 1; o < 256; o <<= 1) {
        int u = (t >= o) ? lp[t - o] : 0;
        __syncthreads();
        lp[t] += u;
        __syncthreads();
    }
    if (t == 255) blockSums[b] = lp[255];
    if (i < n) offsets[i] = lp[t] - v;   // block-local exclusive
}

// phase 2: each block reduces blockSums[0..b-1] (<=78 elems, trivial), adds prefix,
// finalizes offsets + cursor. Fully parallel.
__global__ __launch_bounds__(256) void scan_fixup_kernel(
    const int* __restrict__ blockSums,
    int* __restrict__ offsets, int* __restrict__ cursor, int n, int nb) {
    __shared__ int red[256];
    int t = threadIdx.x, b = blockIdx.x;
    red[t] = (t < b) ? blockSums[t] : 0;
    __syncthreads();
    for (int o = 128; o > 0; o >>= 1) {
        if (t < o) red[t] += red[t + o];
        __syncthreads();
    }
    int prefix = red[0];
    int i = b * 256 + t;
    if (i < n) {
        int val = offsets[i] + prefix;
        offsets[i] = val;
        cursor[i] = val;
    }
    if (b == nb - 1 && t == 0) offsets[n] = prefix + blockSums[b];
}

// fill: single srcs array storing s<<8 (byte offset for 256B rows); gat6 derives *6
// (=> s*1536 for 1536B rows) off the critical path. Halves scatter traffic vs r7.
__global__ void fill_kernel(const int* __restrict__ ei, int* __restrict__ cursor,
                            int* __restrict__ srcs, int E, int n) {
    int t = blockIdx.x * blockDim.x + threadIdx.x;
    if (t < E) {
        int s = ei[t];
        int d = ei[E + t];
        int slot = atomicAdd(&cursor[d], 1);
        srcs[slot] = s << 8;
    } else if (t < E + n) {
        int i = t - E;
        int slot = atomicAdd(&cursor[i], 1);
        srcs[slot] = i << 8;
    }
}

// ---------------- weight/input prep: fp32 -> bf16 TRANSPOSED ([N][K]) ----------------
#define WBIG (1152 * IND)
#define WC1 (768 * HCC)
#define WC2 (192 * HCC)
#define XB_N (NN * IND)
#define PREP_TOTAL (WBIG + WC1 + WC2 + XB_N + 1152 + 768 + 192)

__global__ void prep_kernel(const float* __restrict__ x, const float* __restrict__ inp_w,
    const float* __restrict__ l0wl, const float* __restrict__ l0wr,
    const float* __restrict__ l1wl, const float* __restrict__ l1wr,
    const float* __restrict__ l2wl, const float* __restrict__ l2wr,
    const float* __restrict__ resw,
    const float* __restrict__ inp_b,
    const float* __restrict__ l0bl, const float* __restrict__ l0br,
    const float* __restrict__ l1bl, const float* __restrict__ l1br,
    const float* __restrict__ l2bl, const float* __restrict__ l2br,
    ushort_t* wBig, ushort_t* wC1, ushort_t* wC2, ushort_t* xb,
    float* bBig, float* bC1, float* bC2)
{
    int i = blockIdx.x * blockDim.x + threadIdx.x;
    if (i >= PREP_TOTAL) return;
    if (i < WBIG) {
        int col = i >> 7, k = i & 127;
        float v;
        if (col < 384)      v = inp_w[k * 384 + col];
        else if (col < 768) v = l0wl[k * 384 + (col - 384)];
        else                v = l0wr[k * 384 + (col - 768)];
        wBig[i] = f2bf(v); return;
    }
    i -= WBIG;
    if (i < WC1) {
        int col = i / 384, k = i - col * 384;
        float v = col < 384 ? l1wl[k * 384 + col] : l1wr[k * 384 + (col - 384)];
        wC1[i] = f2bf(v); return;
    }
    i -= WC1;
    if (i < WC2) {
        int col = i / 384, k = i - col * 384;
        float v;
        if (col < 64)       v = resw[k * 64 + col];
        else if (col < 128) v = l2wl[k * 64 + (col - 64)];
        else                v = l2wr[k * 64 + (col - 128)];
        wC2[i] = f2bf(v); return;
    }
    i -= WC2;
    if (i < XB_N) { xb[i] = f2bf(x[i]); return; }
    i -= XB_N;
    if (i < 1152) {
        float v;
        if (i < 384)      v = inp_b[i];
        else if (i < 768) v = l0bl[i - 384];
        else              v = l0br[i - 768];
        bBig[i] = v; return;
    }
    i -= 1152;
    if (i < 768) { bC1[i] = i < 384 ? l1bl[i] : l1br[i - 384]; return; }
    i -= 768;
    if (i < 192) {
        float v;
        if (i < 64)       v = 0.0f;
        else if (i < 128) v = l2bl[i - 64];
        else              v = l2br[i - 128];
        bC2[i] = v; return;
    }
}

// ---------------- bf16 MFMA GEMM (big): M-tile 256, 8 waves, col-tile loop, XCD swizzle ----
// A-reuse grouping: logical decomposed bx = logical/gridDim.y -> the gridDim.y blocks
// sharing the SAME A rows are consecutive logicals = same XCD = A panel L2-resident.
__global__ __launch_bounds__(512) void gemm_mfma2(
    const ushort_t* __restrict__ A, const ushort_t* __restrict__ BT,
    const float* __restrict__ bias,
    ushort_t* __restrict__ Cb1, int ld1,
    ushort_t* __restrict__ Cb2, int ld2, int split,
    int M, int N, int K, int NT)
{
    __shared__ ushort_t Bs[2][2][128 * 32];   // 32 KB
    int t = threadIdx.x;
    int w = t >> 6, L = t & 63;               // w in [0,8)
    int nwg = gridDim.x * gridDim.y;
    int logical = xcd_swz(blockIdx.y * gridDim.x + blockIdx.x, nwg);
    int bx = logical / gridDim.y;             // A-sharing trio consecutive -> same XCD
    int by = logical % gridDim.y;
    int m0 = bx * 256;
    int q = L >> 4, r16 = L & 15;
    int lr = L >> 2;
    int lc = ((L & 3) ^ ((lr >> 1) & 3)) * 8;   // pre-swizzled source chunk
    int sw = (q ^ ((r16 >> 1) & 3)) * 8;        // matching ds_read swizzle
    int oB = (w * 16) * 32;                     // wave stages B rows [w*16, w*16+16)

    int rA0 = min(m0 + w * 32 + r16, M - 1);
    int rA1 = min(m0 + w * 32 + 16 + r16, M - 1);
    const ushort_t* pA0base = A + (size_t)rA0 * K + q * 8;
    const ushort_t* pA1base = A + (size_t)rA1 * K + q * 8;

    for (int nt = 0; nt < NT; ++nt) {
        int n0 = (by * NT + nt) * 128;
        int rB = min(n0 + w * 16 + lr, N - 1);
        const ushort_t* gB = BT + (size_t)rB * K + lc;
        const ushort_t* pA0 = pA0base;
        const ushort_t* pA1 = pA1base;

        f32x4 acc[2][8];
#pragma unroll
        for (int a = 0; a < 2; ++a)
#pragma unroll
            for (int b = 0; b < 8; ++b) acc[a][b] = (f32x4){0.f, 0.f, 0.f, 0.f};

        load_lds16(gB, &Bs[0][0][oB]);
        load_lds16(gB + 32, &Bs[0][1][oB]);
        gB += 64;
        bf16x8 a0 = *(const bf16x8*)pA0;
        bf16x8 a2 = *(const bf16x8*)(pA0 + 32);
        bf16x8 a1 = *(const bf16x8*)pA1;
        bf16x8 a3 = *(const bf16x8*)(pA1 + 32);
        pA0 += 64; pA1 += 64;

        int buf = 0;
        for (int k0 = 0; k0 < K; k0 += 64) {
            __syncthreads();
            bool more = (k0 + 64 < K);
            if (more) {
                int nb = buf ^ 1;
                load_lds16(gB, &Bs[nb][0][oB]);
                load_lds16(gB + 32, &Bs[nb][1][oB]);
                gB += 64;
            }
            bf16x8 na0, na1, na2, na3;
            if (more) {
                na0 = *(const bf16x8*)pA0;
                na2 = *(const bf16x8*)(pA0 + 32);
                na1 = *(const bf16x8*)pA1;
                na3 = *(const bf16x8*)(pA1 + 32);
                pA0 += 64; pA1 += 64;
            }
#pragma unroll
            for (int ct = 0; ct < 8; ++ct) {
                bf16x8 blo = *(const bf16x8*)&Bs[buf][0][(ct * 16 + r16) * 32 + sw];
                bf16x8 bhi = *(const bf16x8*)&Bs[buf][1][(ct * 16 + r16) * 32 + sw];
                acc[0][ct] = __builtin_amdgcn_mfma_f32_16x16x32_bf16(blo, a0, acc[0][ct], 0, 0, 0);
                acc[1][ct] = __builtin_amdgcn_mfma_f32_16x16x32_bf16(blo, a1, acc[1][ct], 0, 0, 0);
                acc[0][ct] = __builtin_amdgcn_mfma_f32_16x16x32_bf16(bhi, a2, acc[0][ct], 0, 0, 0);
                acc[1][ct] = __builtin_amdgcn_mfma_f32_16x16x32_bf16(bhi, a3, acc[1][ct], 0, 0, 0);
            }
            if (more) { a0 = na0; a1 = na1; a2 = na2; a3 = na3; }
            buf ^= 1;
        }
#pragma unroll
        for (int rt = 0; rt < 2; ++rt) {
            int row = m0 + w * 32 + rt * 16 + r16;
            if (row >= M) continue;
#pragma unroll
            for (int ct = 0; ct < 8; ++ct) {
                int colb = n0 + ct * 16 + q * 4;
                if (colb >= N) continue;
                float4 bv = *(const float4*)(bias + colb);
                uint2 pk;
                pk.x = (uint_t)f2bf(acc[rt][ct][0] + bv.x) | ((uint_t)f2bf(acc[rt][ct][1] + bv.y) << 16);
                pk.y = (uint_t)f2bf(acc[rt][ct][2] + bv.z) | ((uint_t)f2bf(acc[rt][ct][3] + bv.w) << 16);
                if (colb < split)
                    *(uint2*)(Cb1 + (size_t)row * ld1 + colb) = pk;
                else
                    *(uint2*)(Cb2 + (size_t)row * ld2 + (colb - split)) = pk;
            }
        }
    }
}

// ---------------- bf16 MFMA GEMM (small, 128-tile): kept for gemm3, XCD swizzle ----------------
__global__ __launch_bounds__(256) void gemm_mfma(
    const ushort_t* __restrict__ A, const ushort_t* __restrict__ BT,
    const float* __restrict__ bias,
    float* __restrict__ Cf, ushort_t* __restrict__ Cb1, int ld1,
    ushort_t* __restrict__ Cb2, int ld2, int split,
    int M, int N, int K)
{
    __shared__ ushort_t Bs[2][2][128 * 32];
    int t = threadIdx.x;
    int w = t >> 6, L = t & 63;
    int nwg = gridDim.x * gridDim.y;
    int logical = xcd_swz(blockIdx.y * gridDim.x + blockIdx.x, nwg);
    int m0 = (logical / gridDim.y) * 128;     // A-sharing pair consecutive -> same XCD
    int n0 = (logical % gridDim.y) * 128;
    int q = L >> 4, r16 = L & 15;

    f32x4 acc[2][8];
#pragma unroll
    for (int a = 0; a < 2; ++a)
#pragma unroll
        for (int b = 0; b < 8; ++b) acc[a][b] = (f32x4){0.f, 0.f, 0.f, 0.f};

    int lr = L >> 2;
    int lc = ((L & 3) ^ ((lr >> 1) & 3)) * 8;
    int rB0 = min(n0 + w * 32 + lr, N - 1);
    int rB1 = min(n0 + w * 32 + 16 + lr, N - 1);
    const ushort_t* gB0 = BT + (size_t)rB0 * K + lc;
    const ushort_t* gB1 = BT + (size_t)rB1 * K + lc;
    int oB0 = (w * 32) * 32;
    int oB1 = (w * 32 + 16) * 32;

    int rA0 = min(m0 + w * 32 + r16, M - 1);
    int rA1 = min(m0 + w * 32 + 16 + r16, M - 1);
    const ushort_t* pA0 = A + (size_t)rA0 * K + q * 8;
    const ushort_t* pA1 = A + (size_t)rA1 * K + q * 8;

    int sw = (q ^ ((r16 >> 1) & 3)) * 8;

    load_lds16(gB0, &Bs[0][0][oB0]);
    load_lds16(gB1, &Bs[0][0][oB1]);
    load_lds16(gB0 + 32, &Bs[0][1][oB0]);
    load_lds16(gB1 + 32, &Bs[0][1][oB1]);
    gB0 += 64; gB1 += 64;
    bf16x8 a0 = *(const bf16x8*)pA0;
    bf16x8 a2 = *(const bf16x8*)(pA0 + 32);
    bf16x8 a1 = *(const bf16x8*)pA1;
    bf16x8 a3 = *(const bf16x8*)(pA1 + 32);
    pA0 += 64; pA1 += 64;

    int buf = 0;
    for (int k0 = 0; k0 < K; k0 += 64) {
        __syncthreads();
        bool more = (k0 + 64 < K);
        if (more) {
            int nb = buf ^ 1;
            load_lds16(gB0, &Bs[nb][0][oB0]);
            load_lds16(gB1, &Bs[nb][0][oB1]);
            load_lds16(gB0 + 32, &Bs[nb][1][oB0]);
            load_lds16(gB1 + 32, &Bs[nb][1][oB1]);
            gB0 += 64; gB1 += 64;
        }
        bf16x8 na0, na1, na2, na3;
        if (more) {
            na0 = *(const bf16x8*)pA0;
            na2 = *(const bf16x8*)(pA0 + 32);
            na1 = *(const bf16x8*)pA1;
            na3 = *(const bf16x8*)(pA1 + 32);
            pA0 += 64; pA1 += 64;
        }
#pragma unroll
        for (int ct = 0; ct < 8; ++ct) {
            bf16x8 blo = *(const bf16x8*)&Bs[buf][0][(ct * 16 + r16) * 32 + sw];
            bf16x8 bhi = *(const bf16x8*)&Bs[buf][1][(ct * 16 + r16) * 32 + sw];
            acc[0][ct] = __builtin_amdgcn_mfma_f32_16x16x32_bf16(blo, a0, acc[0][ct], 0, 0, 0);
            acc[1][ct] = __builtin_amdgcn_mfma_f32_16x16x32_bf16(blo, a1, acc[1][ct], 0, 0, 0);
            acc[0][ct] = __builtin_amdgcn_mfma_f32_16x16x32_bf16(bhi, a2, acc[0][ct], 0, 0, 0);
            acc[1][ct] = __builtin_amdgcn_mfma_f32_16x16x32_bf16(bhi, a3, acc[1][ct], 0, 0, 0);
        }
        if (more) { a0 = na0; a1 = na1; a2 = na2; a3 = na3; }
        buf ^= 1;
    }
#pragma unroll
    for (int rt = 0; rt < 2; ++rt) {
        int row = m0 + w * 32 + rt * 16 + r16;
        if (row >= M) continue;
#pragma unroll
        for (int ct = 0; ct < 8; ++ct) {
            int colb = n0 + ct * 16 + q * 4;
            if (colb >= N) continue;
            float4 bv = *(const float4*)(bias + colb);
            float v0 = acc[rt][ct][0] + bv.x;
            float v1 = acc[rt][ct][1] + bv.y;
            float v2 = acc[rt][ct][2] + bv.z;
            float v3 = acc[rt][ct][3] + bv.w;
            if (colb < split) {
                if (Cf) {
                    *(float4*)(Cf + (size_t)row * ld1 + colb) = make_float4(v0, v1, v2, v3);
                } else {
                    uint2 pk;
                    pk.x = (uint_t)f2bf(v0) | ((uint_t)f2bf(v1) << 16);
                    pk.y = (uint_t)f2bf(v2) | ((uint_t)f2bf(v3) << 16);
                    *(uint2*)(Cb1 + (size_t)row * ld1 + colb) = pk;
                }
            } else {
                uint2 pk;
                pk.x = (uint_t)f2bf(v0) | ((uint_t)f2bf(v1) << 16);
                pk.y = (uint_t)f2bf(v2) | ((uint_t)f2bf(v3) << 16);
                *(uint2*)(Cb2 + (size_t)row * ld2 + (colb - split)) = pk;
            }
        }
    }
}

// ---------------- GATv2 H=6: branchless 1-deep pair loop, srcs = s<<8 (derive *6) ----------------
__global__ __launch_bounds__(128) void gat6_kernel(
    const ushort_t* __restrict__ cat, const float* __restrict__ att,
    const float* __restrict__ bias, const ushort_t* __restrict__ resB,
    ushort_t* __restrict__ outB,
    const int* __restrict__ offsets, const int* __restrict__ srcs, int n)
{
    int wid = (blockIdx.x * blockDim.x + threadIdx.x) >> 6;
    if (wid >= n) return;
    int lane = threadIdx.x & 63;
    int h = lane >> 3, c8 = lane & 7;
    bool hv = h < HH;
    int off = h * 64 + c8 * 8;
    int offL2 = (hv ? off : off - 384) * 2;   // BYTE offset; invalid lanes alias groups 0/1
    int i = wid;
    int beg = __builtin_amdgcn_readfirstlane(offsets[i]);
    int end = __builtin_amdgcn_readfirstlane(offsets[i + 1]);
    int deg = end - beg;
    int P = (deg + 1) >> 1;
    const char* catc = (const char*)cat;

    f32x2 xr2[4], att2[4];
    {
        uint4 v = *(const uint4*)(catc + (size_t)i * 1536 + 768 + offL2);
        bf8cvt2(v, xr2);
    }
#pragma unroll
    for (int j = 0; j < 4; ++j) {
        int o = (offL2 >> 1) + 2 * j;
        att2[j] = (f32x2){att[o] * LOG2E, att[o + 1] * LOG2E};
    }

    float s = 0.0f;
    f32x2 acc2[4];
#pragma unroll
    for (int j = 0; j < 4; ++j) acc2[j] = (f32x2){0.f, 0.f};

    int bA0 = srcs[beg] * 6, bB0 = srcs[beg + 1] * 6;   // s<<8 -> s*1536
    uint4 cA = *(const uint4*)(catc + (size_t)(uint_t)bA0 + offL2);
    uint4 cB = *(const uint4*)(catc + (size_t)(uint_t)bB0 + offL2);
    int iA1 = srcs[beg + 2] * 6, iB1 = srcs[beg + 3] * 6;

    for (int p = 0; p < P; ++p) {
        uint4 nA = cA, nB = cB;
        bool pre = (p + 1 < P);       // uniform branch: skip useless last prefetch
        if (pre) {
            nA = *(const uint4*)(catc + (size_t)(uint_t)iA1 + offL2);
            nB = *(const uint4*)(catc + (size_t)(uint_t)iB1 + offL2);
            iA1 = srcs[beg + 2 * p + 4] * 6;
            iB1 = srcs[beg + 2 * p + 5] * 6;
        }
        f32x2 xlA[4], xlB[4];
        bf8cvt2(cA, xlA);
        bf8cvt2(cB, xlB);
        f32x2 pA2 = (f32x2){0.f, 0.f}, pB2 = (f32x2){0.f, 0.f};
#pragma unroll
        for (int j = 0; j < 4; ++j) {
            f32x2 ta = xlA[j] + xr2[j];
            ta = __builtin_elementwise_max(ta, ta * 0.2f);
            pA2 += ta * att2[j];
            f32x2 tb = xlB[j] + xr2[j];
            tb = __builtin_elementwise_max(tb, tb * 0.2f);
            pB2 += tb * att2[j];
        }
        float pA = pA2.x + pA2.y, pB = pB2.x + pB2.y;
        pA = dppadd<0xB1>(pA);
        pB = dppadd<0xB1>(pB);
        pA = dppadd<0x4E>(pA);
        pB = dppadd<0x4E>(pB);
        pA = dppadd<0x141>(pA);
        pB = dppadd<0x141>(pB);
        float wA = __builtin_amdgcn_exp2f(pA);
        float wB = (2 * p + 1 < deg) ? __builtin_amdgcn_exp2f(pB) : 0.0f;
        s += wA + wB;
        f32x2 wA2 = (f32x2){wA, wA}, wB2 = (f32x2){wB, wB};
#pragma unroll
        for (int j = 0; j < 4; ++j) {
            acc2[j] += wA2 * xlA[j];
            acc2[j] += wB2 * xlB[j];
        }
        cA = nA; cB = nB;
    }

    if (hv) {
        float inv = 1.0f / (s + 1e-16f);
        size_t ob = (size_t)i * HCC + off;
        uint4 rv = *(const uint4*)(resB + ob);
        f32x2 rr[4];
        bf8cvt2(rv, rr);
        ushort_t u[8];
#pragma unroll
        for (int j = 0; j < 4; ++j) {
            float v0 = acc2[j].x * inv + bias[off + 2 * j];
            float v1 = acc2[j].y * inv + bias[off + 2 * j + 1];
            v0 = v0 > 0.0f ? v0 : expm1f(v0);
            v1 = v1 > 0.0f ? v1 : expm1f(v1);
            u[2 * j]     = f2bf(v0 + rr[j].x);
            u[2 * j + 1] = f2bf(v1 + rr[j].y);
        }
        *(uint4*)(outB + ob) = *(uint4*)u;
    }
}

// ---------------- GATv2 H=1: single-pass exp2-folded, DPP reduce, srcs = s<<8 ----------------
__global__ __launch_bounds__(128) void gat1_kernel(
    const ushort_t* __restrict__ cat, const float* __restrict__ att,
    const float* __restrict__ bias, const float* __restrict__ res,
    float* __restrict__ out,
    const int* __restrict__ offsets, const int* __restrict__ srcs, int n)
{
    int wid = (blockIdx.x * blockDim.x + threadIdx.x) >> 6;
    if (wid >= n) return;
    int lane = threadIdx.x & 63;
    int e8 = lane >> 3, c8 = lane & 7;
    int i = wid;
    int beg = __builtin_amdgcn_readfirstlane(offsets[i]);
    int end = __builtin_amdgcn_readfirstlane(offsets[i + 1]);
    const char* catc = (const char*)cat;

    f32x2 xr2[4], att2[4];
    {
        uint4 v = *(const uint4*)(cat + (size_t)i * 128 + 64 + c8 * 8);
        bf8cvt2(v, xr2);
    }
#pragma unroll
    for (int j = 0; j < 4; ++j)
        att2[j] = (f32x2){att[c8 * 8 + 2 * j] * LOG2E, att[c8 * 8 + 2 * j + 1] * LOG2E};

    float s = 0.0f;
    f32x2 acc2[4];
#pragma unroll
    for (int j = 0; j < 4; ++j) acc2[j] = (f32x2){0.f, 0.f};

    const uint4 z = make_uint4(0u, 0u, 0u, 0u);
    int p = beg + e8;
    bool val = p < end;
    int b = val ? srcs[p] : (i << 8);
    uint4 v = *(const uint4*)(catc + (size_t)(uint_t)b + c8 * 16);

    for (int p0 = beg; p0 < end; p0 += 8) {
        uint4 nv = z;
        bool nval = false;
        if (p0 + 8 < end) {
            int np = p0 + 8 + e8;
            nval = np < end;
            int nb = nval ? srcs[np] : (i << 8);
            nv = *(const uint4*)(catc + (size_t)(uint_t)nb + c8 * 16);
        }
        f32x2 xl[4];
        bf8cvt2(v, xl);
        f32x2 pp2 = (f32x2){0.f, 0.f};
#pragma unroll
        for (int j = 0; j < 4; ++j) {
            f32x2 tv = xl[j] + xr2[j];
            tv = __builtin_elementwise_max(tv, tv * 0.2f);
            pp2 += tv * att2[j];
        }
        float partial = pp2.x + pp2.y;
        partial = dppadd<0xB1>(partial);
        partial = dppadd<0x4E>(partial);
        partial = dppadd<0x141>(partial);
        float wE = val ? __builtin_amdgcn_exp2f(partial) : 0.0f;
        s += wE;
        f32x2 w2 = (f32x2){wE, wE};
#pragma unroll
        for (int j = 0; j < 4; ++j) acc2[j] += w2 * xl[j];
        v = nv;
        val = nval;
    }

    s = dppadd<0x140>(s);
    s += __shfl_xor(s, 16, 64);
    s += __shfl_xor(s, 32, 64);
#pragma unroll
    for (int j = 0; j < 4; ++j) {
        acc2[j].x += __shfl_xor(acc2[j].x, 8, 64);
        acc2[j].y += __shfl_xor(acc2[j].y, 8, 64);
        acc2[j].x += __shfl_xor(acc2[j].x, 16, 64);
        acc2[j].y += __shfl_xor(acc2[j].y, 16, 64);
        acc2[j].x += __shfl_xor(acc2[j].x, 32, 64);
        acc2[j].y += __shfl_xor(acc2[j].y, 32, 64);
    }
    if (e8 == 0) {
        float inv = 1.0f / (s + 1e-16f);
        size_t ob = (size_t)i * CC + c8 * 8;
        float4 r0 = *(const float4*)(res + ob);
        float4 r1 = *(const float4*)(res + ob + 4);
        float rr[8] = {r0.x, r0.y, r0.z, r0.w, r1.x, r1.y, r1.z, r1.w};
        float av[8] = {acc2[0].x, acc2[0].y, acc2[1].x, acc2[1].y,
                       acc2[2].x, acc2[2].y, acc2[3].x, acc2[3].y};
#pragma unroll
        for (int j = 0; j < 8; ++j) {
            float v2 = av[j] * inv + bias[c8 * 8 + j];
            v2 = v2 > 0.0f ? v2 : expm1f(v2);
            av[j] = v2 + rr[j];
        }
        *(float4*)(out + ob) = make_float4(av[0], av[1], av[2], av[3]);
        *(float4*)(out + ob + 4) = make_float4(av[4], av[5], av[6], av[7]);
    }
}

// ---------------- pooling: 4 blocks per group (batch sorted), one atomic per block ----------------
__global__ __launch_bounds__(256) void pool_kernel(const float* __restrict__ h,
                                                   const int* __restrict__ batch,
                                                   float* __restrict__ pooled, int n) {
    int b = blockIdx.x;            // NG*4 blocks
    int g = b >> 2, qd = b & 3;
    int t = threadIdx.x;           // 256
    int w = t >> 6, lane = t & 63;
    int lo = 0, hi = n;
    while (lo < hi) { int mid = (lo + hi) >> 1; if (batch[mid] < g) lo = mid + 1; else hi = mid; }
    int start = lo;
    int hi2 = n;
    while (lo < hi2) { int mid = (lo + hi2) >> 1; if (batch[mid] < g + 1) lo = mid + 1; else hi2 = mid; }
    int endd = lo;
    int len = endd - start;
    int q0 = start + (len * qd) / 4;
    int q1 = start + (len * (qd + 1)) / 4;
    float acc = 0.0f;
    for (int r = q0 + w; r < q1; r += 4)
        acc += h[(size_t)r * 64 + lane];
    __shared__ float red[4][64];
    red[w][lane] = acc;
    __syncthreads();
    if (w == 0) {
        float v2 = red[0][lane] + red[1][lane] + red[2][lane] + red[3][lane];
        atomicAdd(&pooled[g * 64 + lane], v2);
    }
}

// ---------------- dense head: LDS-staged operands ----------------
__global__ __launch_bounds__(256) void head_kernel(const float* __restrict__ pooled,
                            const float* __restrict__ d1w, const float* __restrict__ d1b,
                            const float* __restrict__ bng, const float* __restrict__ bnb,
                            const float* __restrict__ bnm, const float* __restrict__ bnv,
                            const float* __restrict__ d2w, const float* __restrict__ d2b,
                            float* __restrict__ zout) {
    __shared__ float pl[64 * 64];   // 16 KB
    __shared__ float w1[64 * 64];   // 16 KB
    __shared__ float w2[64 * NCC];  // 4 KB
    __shared__ float z1[64 * 64];   // 16 KB
    int t = threadIdx.x;  // 256
    for (int i = t * 4; i < 64 * 64; i += 1024) {
        *(float4*)&pl[i] = *(const float4*)&pooled[i];
        *(float4*)&w1[i] = *(const float4*)&d1w[i];
    }
    for (int i = t * 4; i < 64 * NCC; i += 1024)
        *(float4*)&w2[i] = *(const float4*)&d2w[i];
    __syncthreads();
    for (int idx = t; idx < 64 * 64; idx += 256) {
        int r = idx >> 6, c = idx & 63;
        float acc = d1b[c];
        for (int k = 0; k < 64; ++k) acc += pl[r * 64 + k] * w1[k * 64 + c];
        acc = (acc - bnm[c]) / sqrtf(bnv[c] + 1e-5f) * bng[c] + bnb[c];
        z1[idx] = acc > 0.0f ? acc : 0.0f;
    }
    __syncthreads();
    for (int idx = t; idx < 64 * NCC; idx += 256) {
        int r = idx >> 4, c = idx & 15;
        float acc = d2b[c];
        for (int k = 0; k < 64; ++k) acc += z1[r * 64 + k] * w2[k * NCC + c];
        zout[idx] = acc;
    }
}

// ---------------- launcher ----------------

extern "C" void kernel_launch(void* const* d_in, const int* in_sizes, int n_in,
                              void* d_out, int out_size, void* d_ws, size_t ws_size,
                              hipStream_t stream) {
    const int N = NN, E = EE, C = CC, HC = HCC, NG = NGG;
    const int EN = E + N;

    const float* x     = (const float*)d_in[0];
    const int*   ei    = (const int*)d_in[1];
    const int*   batch = (const int*)d_in[2];
    const float* inp_w = (const float*)d_in[3];
    const float* inp_b = (const float*)d_in[4];
    const float* l0_wl = (const float*)d_in[5];
    const float* l0_bl = (const float*)d_in[6];
    const float* l0_wr = (const float*)d_in[7];
    const float* l0_br = (const float*)d_in[8];
    const float* l0_att = (const float*)d_in[9];
    const float* l0_bias = (const float*)d_in[10];
    const float* l1_wl = (const float*)d_in[11];
    const float* l1_bl = (const float*)d_in[12];
    const float* l1_wr = (const float*)d_in[13];
    const float* l1_br = (const float*)d_in[14];
    const float* l1_att = (const float*)d_in[15];
    const float* l1_bias = (const float*)d_in[16];
    const float* l2_wl = (const float*)d_in[17];
    const float* l2_bl = (const float*)d_in[18];
    const float* l2_wr = (const float*)d_in[19];
    const float* l2_br = (const float*)d_in[20];
    const float* l2_att = (const float*)d_in[21];
    const float* l2_bias = (const float*)d_in[22];
    const float* res_w = (const float*)d_in[23];
    const float* d1_w = (const float*)d_in[24];
    const float* d1_b = (const float*)d_in[25];
    const float* bn_g = (const float*)d_in[26];
    const float* bn_b = (const float*)d_in[27];
    const float* bn_m = (const float*)d_in[28];
    const float* bn_v = (const float*)d_in[29];
    const float* d2_w = (const float*)d_in[30];
    const float* d2_b = (const float*)d_in[31];

    float* out = (float*)d_out;

    char* ws = (char*)d_ws;
    size_t off = 0;
    auto alloc = [&](size_t bytes) -> void* {
        void* p = ws + off;
        off += (bytes + 255) & ~(size_t)255;
        return p;
    };
    ushort_t* bufH_b  = (ushort_t*)alloc((size_t)N * HC * 2);
    ushort_t* cat01_b = (ushort_t*)alloc((size_t)N * 768 * 2 + 2048);
    ushort_t* xres_b  = (ushort_t*)alloc((size_t)N * HC * 2);
    ushort_t* cat2_b  = (ushort_t*)alloc((size_t)N * 128 * 2);
    float*    bufRes  = (float*)alloc((size_t)N * C * 4);
    ushort_t* xb      = (ushort_t*)alloc((size_t)N * IND * 2);
    ushort_t* wBig    = (ushort_t*)alloc((size_t)WBIG * 2);
    ushort_t* wC1     = (ushort_t*)alloc((size_t)WC1 * 2);
    ushort_t* wC2     = (ushort_t*)alloc((size_t)WC2 * 2);
    float*    bBig    = (float*)alloc((size_t)1152 * 4);
    float*    bC1     = (float*)alloc((size_t)768 * 4);
    float*    bC2     = (float*)alloc((size_t)192 * 4);
    int*      counts  = (int*)alloc((size_t)N * 4);
    int*      cursor  = (int*)alloc((size_t)N * 4);
    int*      offsets = (int*)alloc((size_t)(N + 1) * 4);
    int*      srcs    = (int*)alloc((size_t)(EN + 8) * 4);   // s<<8 byte offsets + pad
    int*      blockSums = (int*)alloc((size_t)256 * 4);
    float*    pooled  = (float*)alloc((size_t)NG * C * 4);

    const int SCAN_NB = (N + 255) / 256;   // 79

    zero_init_kernel<<<(N + 255) / 256, 256, 0, stream>>>(counts, srcs + EN,
                                                          pooled, N, NG * C);
    count_kernel<<<(E + 255) / 256, 256, 0, stream>>>(ei, counts, E);
    scan_local_kernel<<<SCAN_NB, 256, 0, stream>>>(counts, offsets, blockSums, N);
    scan_fixup_kernel<<<SCAN_NB, 256, 0, stream>>>(blockSums, offsets, cursor, N, SCAN_NB);
    fill_kernel<<<(EN + 255) / 256, 256, 0, stream>>>(ei, cursor, srcs, E, N);
    prep_kernel<<<(PREP_TOTAL + 255) / 256, 256, 0, stream>>>(
        x, inp_w, l0_wl, l0_wr, l1_wl, l1_wr, l2_wl, l2_wr, res_w,
        inp_b, l0_bl, l0_br, l1_bl, l1_br, l2_bl, l2_br,
        wBig, wC1, wC2, xb, bBig, bC1, bC2);

    int mtiles256 = (N + 255) / 256;   // 79
    int mtiles = (N + 127) / 128;      // 157
    dim3 gblk(128);
    int gatBlocks = (N * 64 + 127) / 128;

    // fused: [x_res | l0_xl | l0_xr] = xb @ wBig (bf16 out; split at 384). 9 col-tiles = 3y x NT3
    gemm_mfma2<<<dim3(mtiles256, 3), dim3(512), 0, stream>>>(xb, wBig, bBig,
        xres_b, HC, cat01_b, 768, 384, N, 1152, IND, 3);
    gat6_kernel<<<gatBlocks, gblk, 0, stream>>>(cat01_b, l0_att, l0_bias,
                                                xres_b, bufH_b, offsets, srcs, N);
    // layer 1: [l1_xl | l1_xr] = h0 @ wC1. 6 col-tiles = 3y x NT2
    gemm_mfma2<<<dim3(mtiles256, 3), dim3(512), 0, stream>>>(bufH_b, wC1, bC1,
        nullptr, 0, cat01_b, 768, 0, N, 768, HC, 2);
    gat6_kernel<<<gatBlocks, gblk, 0, stream>>>(cat01_b, l1_att, l1_bias,
                                                bufH_b, bufH_b, offsets, srcs, N);
    // fused: [res | l2_xl | l2_xr] = h1 @ wC2 (res fp32, rest bf16) — small, keep 128-tile
    gemm_mfma<<<dim3(mtiles, 2), dim3(256), 0, stream>>>(bufH_b, wC2, bC2,
        bufRes, nullptr, C, cat2_b, 128, 64, N, 192, HC);
    gat1_kernel<<<gatBlocks, gblk, 0, stream>>>(cat2_b, l2_att, l2_bias,
                                                bufRes, out, offsets, srcs, N);
    // pooling + head
    pool_kernel<<<NG * 4, 256, 0, stream>>>(out, batch, pooled, N);
    head_kernel<<<1, 256, 0, stream>>>(pooled, d1_w, d1_b, bn_g, bn_b, bn_m, bn_v,
                                       d2_w, d2_b, out + (size_t)N * C);
}

// Round 9
// 372.132 us; speedup vs baseline: 2.0226x; 1.0593x over previous
//
#include <hip/hip_runtime.h>
#include <hip/hip_bf16.h>
#include <math.h>

#define NN 20000
#define EE 320000
#define IND 128
#define HH 6
#define CC 64
#define HCC 384
#define NCC 16
#define NGG 64

typedef __bf16 bf16x8 __attribute__((ext_vector_type(8)));
typedef float f32x4 __attribute__((ext_vector_type(4)));
typedef float f32x2 __attribute__((ext_vector_type(2)));
typedef unsigned short ushort_t;
typedef unsigned int uint_t;

#define LOG2E 1.44269504088896f

__device__ inline ushort_t f2bf(float f) {
    union { float f; uint_t u; } x; x.f = f;
    uint_t r = (x.u + 0x7FFF + ((x.u >> 16) & 1)) >> 16;
    return (ushort_t)r;
}
// 8 packed bf16 (uint4) -> 4 f32x2 (pairs) for packed-f32 VALU
__device__ inline void bf8cvt2(uint4 v, f32x2* f) {
    union { uint_t u; float x; } a, b;
    a.u = v.x << 16; b.u = v.x & 0xFFFF0000u; f[0] = (f32x2){a.x, b.x};
    a.u = v.y << 16; b.u = v.y & 0xFFFF0000u; f[1] = (f32x2){a.x, b.x};
    a.u = v.z << 16; b.u = v.z & 0xFFFF0000u; f[2] = (f32x2){a.x, b.x};
    a.u = v.w << 16; b.u = v.w & 0xFFFF0000u; f[3] = (f32x2){a.x, b.x};
}

// DPP cross-lane add (VALU, no DS pipe). CTRL: 0xB1=xor1, 0x4E=xor2,
// 0x141=row_half_mirror (==xor4 once quad-uniform), 0x140=row_mirror (==xor8).
template <int CTRL>
__device__ inline float dppadd(float x) {
    int y = __builtin_amdgcn_mov_dpp(__builtin_bit_cast(int, x), CTRL, 0xF, 0xF, true);
    return x + __builtin_bit_cast(float, y);
}

// async global->LDS: lane L writes lds+16*L
__device__ inline void load_lds16(const ushort_t* g, ushort_t* l) {
    __builtin_amdgcn_global_load_lds(
        (const __attribute__((address_space(1))) void*)g,
        (__attribute__((address_space(3))) void*)l, 16, 0, 0);
}

// bijective XCD swizzle (m204): consecutive logical ids land on the SAME XCD.
// lin = HW launch order (lin%8 -> XCD). Returns logical tile id.
__device__ inline int xcd_swz(int lin, int nwg) {
    int q = nwg >> 3, r = nwg & 7;
    int xc = lin & 7, j = lin >> 3;
    return (xc < r ? xc * (q + 1) : r * (q + 1) + (xc - r) * q) + j;
}

// ---------------- utility kernels ----------------

__global__ void zero_init_kernel(int* counts, int* srcs_tail,
                                 float* pooled, int n, int np) {
    int t = blockIdx.x * blockDim.x + threadIdx.x;
    if (t < n) counts[t] = 0;
    if (t < np) pooled[t] = 0.0f;
    if (t < 32) srcs_tail[t] = 0;    // pad covers gat1's 16-edge group over-read
}

__global__ void count_kernel(const int* __restrict__ ei, int* __restrict__ counts, int E) {
    int t = blockIdx.x * blockDim.x + threadIdx.x;
    if (t < E) atomicAdd(&counts[ei[E + t]], 1);
}

// distributed scan: phase 1 per-block exclusive scan of (counts+1); block totals out.
__global__ __launch_bounds__(256) void scan_local_kernel(
    const int* __restrict__ counts, int* __restrict__ offsets,
    int* __restrict__ blockSums, int n) {
    __shared__ int lp[256];
    int t = threadIdx.x, b = blockIdx.x;
    int i = b * 256 + t;
    int v = (i < n) ? counts[i] + 1 : 0;
    lp[t] = v;
    __syncthreads();
    for (int o = 1; o < 256; o <<= 1) {
        int u = (t >= o) ? lp[t - o] : 0;
        __syncthreads();
        lp[t] += u;
        __syncthreads();
    }
    if (t == 255) blockSums[b] = lp[255];
    if (i < n) offsets[i] = lp[t] - v;   // block-local exclusive
}

// phase 2: add scanned block prefix, finalize offsets + cursor.
__global__ __launch_bounds__(256) void scan_fixup_kernel(
    const int* __restrict__ blockSums,
    int* __restrict__ offsets, int* __restrict__ cursor, int n, int nb) {
    __shared__ int red[256];
    int t = threadIdx.x, b = blockIdx.x;
    red[t] = (t < b) ? blockSums[t] : 0;
    __syncthreads();
    for (int o = 128; o > 0; o >>= 1) {
        if (t < o) red[t] += red[t + o];
        __syncthreads();
    }
    int prefix = red[0];
    int i = b * 256 + t;
    if (i < n) {
        int val = offsets[i] + prefix;
        offsets[i] = val;
        cursor[i] = val;
    }
    if (b == nb - 1 && t == 0) offsets[n] = prefix + blockSums[b];
}

// fill: single srcs array storing s<<8 (byte offset for 256B rows); gat6 derives *6.
__global__ void fill_kernel(const int* __restrict__ ei, int* __restrict__ cursor,
                            int* __restrict__ srcs, int E, int n) {
    int t = blockIdx.x * blockDim.x + threadIdx.x;
    if (t < E) {
        int s = ei[t];
        int d = ei[E + t];
        int slot = atomicAdd(&cursor[d], 1);
        srcs[slot] = s << 8;
    } else if (t < E + n) {
        int i = t - E;
        int slot = atomicAdd(&cursor[i], 1);
        srcs[slot] = i << 8;
    }
}

// ---------------- weight/input prep: fp32 -> bf16 TRANSPOSED ([N][K]) ----------------
#define WBIG (1152 * IND)
#define WC1 (768 * HCC)
#define WC2 (192 * HCC)
#define XB_N (NN * IND)
#define PREP_TOTAL (WBIG + WC1 + WC2 + XB_N + 1152 + 768 + 192)

__global__ void prep_kernel(const float* __restrict__ x, const float* __restrict__ inp_w,
    const float* __restrict__ l0wl, const float* __restrict__ l0wr,
    const float* __restrict__ l1wl, const float* __restrict__ l1wr,
    const float* __restrict__ l2wl, const float* __restrict__ l2wr,
    const float* __restrict__ resw,
    const float* __restrict__ inp_b,
    const float* __restrict__ l0bl, const float* __restrict__ l0br,
    const float* __restrict__ l1bl, const float* __restrict__ l1br,
    const float* __restrict__ l2bl, const float* __restrict__ l2br,
    ushort_t* wBig, ushort_t* wC1, ushort_t* wC2, ushort_t* xb,
    float* bBig, float* bC1, float* bC2)
{
    int i = blockIdx.x * blockDim.x + threadIdx.x;
    if (i >= PREP_TOTAL) return;
    if (i < WBIG) {
        int col = i >> 7, k = i & 127;
        float v;
        if (col < 384)      v = inp_w[k * 384 + col];
        else if (col < 768) v = l0wl[k * 384 + (col - 384)];
        else                v = l0wr[k * 384 + (col - 768)];
        wBig[i] = f2bf(v); return;
    }
    i -= WBIG;
    if (i < WC1) {
        int col = i / 384, k = i - col * 384;
        float v = col < 384 ? l1wl[k * 384 + col] : l1wr[k * 384 + (col - 384)];
        wC1[i] = f2bf(v); return;
    }
    i -= WC1;
    if (i < WC2) {
        int col = i / 384, k = i - col * 384;
        float v;
        if (col < 64)       v = resw[k * 64 + col];
        else if (col < 128) v = l2wl[k * 64 + (col - 64)];
        else                v = l2wr[k * 64 + (col - 128)];
        wC2[i] = f2bf(v); return;
    }
    i -= WC2;
    if (i < XB_N) { xb[i] = f2bf(x[i]); return; }
    i -= XB_N;
    if (i < 1152) {
        float v;
        if (i < 384)      v = inp_b[i];
        else if (i < 768) v = l0bl[i - 384];
        else              v = l0br[i - 768];
        bBig[i] = v; return;
    }
    i -= 1152;
    if (i < 768) { bC1[i] = i < 384 ? l1bl[i] : l1br[i - 384]; return; }
    i -= 768;
    if (i < 192) {
        float v;
        if (i < 64)       v = 0.0f;
        else if (i < 128) v = l2bl[i - 64];
        else              v = l2br[i - 128];
        bC2[i] = v; return;
    }
}

// ---------------- bf16 MFMA GEMM (128-tile, 4 waves): ALL gemms ----------------
// r8 lesson: the 256-tile NT-loop version cut traffic but had only 237 blocks
// (0.93/CU) -> prologue latency fully exposed (r5 neutral-to-negative). 128-tile
// grids give 1413/942/314 blocks = 3-5/CU: cross-block TLP hides the k-loop
// prologue (m114 mechanism). XCD swizzle groups same-A-panel blocks per XCD.
__global__ __launch_bounds__(256) void gemm_mfma(
    const ushort_t* __restrict__ A, const ushort_t* __restrict__ BT,
    const float* __restrict__ bias,
    float* __restrict__ Cf, ushort_t* __restrict__ Cb1, int ld1,
    ushort_t* __restrict__ Cb2, int ld2, int split,
    int M, int N, int K)
{
    __shared__ ushort_t Bs[2][2][128 * 32];
    int t = threadIdx.x;
    int w = t >> 6, L = t & 63;
    int nwg = gridDim.x * gridDim.y;
    int logical = xcd_swz(blockIdx.y * gridDim.x + blockIdx.x, nwg);
    int m0 = (logical / gridDim.y) * 128;     // A-sharing group consecutive -> same XCD
    int n0 = (logical % gridDim.y) * 128;
    int q = L >> 4, r16 = L & 15;

    f32x4 acc[2][8];
#pragma unroll
    for (int a = 0; a < 2; ++a)
#pragma unroll
        for (int b = 0; b < 8; ++b) acc[a][b] = (f32x4){0.f, 0.f, 0.f, 0.f};

    int lr = L >> 2;
    int lc = ((L & 3) ^ ((lr >> 1) & 3)) * 8;
    int rB0 = min(n0 + w * 32 + lr, N - 1);
    int rB1 = min(n0 + w * 32 + 16 + lr, N - 1);
    const ushort_t* gB0 = BT + (size_t)rB0 * K + lc;
    const ushort_t* gB1 = BT + (size_t)rB1 * K + lc;
    int oB0 = (w * 32) * 32;
    int oB1 = (w * 32 + 16) * 32;

    int rA0 = min(m0 + w * 32 + r16, M - 1);
    int rA1 = min(m0 + w * 32 + 16 + r16, M - 1);
    const ushort_t* pA0 = A + (size_t)rA0 * K + q * 8;
    const ushort_t* pA1 = A + (size_t)rA1 * K + q * 8;

    int sw = (q ^ ((r16 >> 1) & 3)) * 8;

    load_lds16(gB0, &Bs[0][0][oB0]);
    load_lds16(gB1, &Bs[0][0][oB1]);
    load_lds16(gB0 + 32, &Bs[0][1][oB0]);
    load_lds16(gB1 + 32, &Bs[0][1][oB1]);
    gB0 += 64; gB1 += 64;
    bf16x8 a0 = *(const bf16x8*)pA0;
    bf16x8 a2 = *(const bf16x8*)(pA0 + 32);
    bf16x8 a1 = *(const bf16x8*)pA1;
    bf16x8 a3 = *(const bf16x8*)(pA1 + 32);
    pA0 += 64; pA1 += 64;

    int buf = 0;
    for (int k0 = 0; k0 < K; k0 += 64) {
        __syncthreads();
        bool more = (k0 + 64 < K);
        if (more) {
            int nb = buf ^ 1;
            load_lds16(gB0, &Bs[nb][0][oB0]);
            load_lds16(gB1, &Bs[nb][0][oB1]);
            load_lds16(gB0 + 32, &Bs[nb][1][oB0]);
            load_lds16(gB1 + 32, &Bs[nb][1][oB1]);
            gB0 += 64; gB1 += 64;
        }
        bf16x8 na0, na1, na2, na3;
        if (more) {
            na0 = *(const bf16x8*)pA0;
            na2 = *(const bf16x8*)(pA0 + 32);
            na1 = *(const bf16x8*)pA1;
            na3 = *(const bf16x8*)(pA1 + 32);
            pA0 += 64; pA1 += 64;
        }
#pragma unroll
        for (int ct = 0; ct < 8; ++ct) {
            bf16x8 blo = *(const bf16x8*)&Bs[buf][0][(ct * 16 + r16) * 32 + sw];
            bf16x8 bhi = *(const bf16x8*)&Bs[buf][1][(ct * 16 + r16) * 32 + sw];
            // swapped operands: lane holds row (m0+..+r16), cols q*4+reg
            acc[0][ct] = __builtin_amdgcn_mfma_f32_16x16x32_bf16(blo, a0, acc[0][ct], 0, 0, 0);
            acc[1][ct] = __builtin_amdgcn_mfma_f32_16x16x32_bf16(blo, a1, acc[1][ct], 0, 0, 0);
            acc[0][ct] = __builtin_amdgcn_mfma_f32_16x16x32_bf16(bhi, a2, acc[0][ct], 0, 0, 0);
            acc[1][ct] = __builtin_amdgcn_mfma_f32_16x16x32_bf16(bhi, a3, acc[1][ct], 0, 0, 0);
        }
        if (more) { a0 = na0; a1 = na1; a2 = na2; a3 = na3; }
        buf ^= 1;
    }
#pragma unroll
    for (int rt = 0; rt < 2; ++rt) {
        int row = m0 + w * 32 + rt * 16 + r16;
        if (row >= M) continue;
#pragma unroll
        for (int ct = 0; ct < 8; ++ct) {
            int colb = n0 + ct * 16 + q * 4;
            if (colb >= N) continue;
            float4 bv = *(const float4*)(bias + colb);
            float v0 = acc[rt][ct][0] + bv.x;
            float v1 = acc[rt][ct][1] + bv.y;
            float v2 = acc[rt][ct][2] + bv.z;
            float v3 = acc[rt][ct][3] + bv.w;
            if (colb < split) {
                if (Cf) {
                    *(float4*)(Cf + (size_t)row * ld1 + colb) = make_float4(v0, v1, v2, v3);
                } else {
                    uint2 pk;
                    pk.x = (uint_t)f2bf(v0) | ((uint_t)f2bf(v1) << 16);
                    pk.y = (uint_t)f2bf(v2) | ((uint_t)f2bf(v3) << 16);
                    *(uint2*)(Cb1 + (size_t)row * ld1 + colb) = pk;
                }
            } else {
                uint2 pk;
                pk.x = (uint_t)f2bf(v0) | ((uint_t)f2bf(v1) << 16);
                pk.y = (uint_t)f2bf(v2) | ((uint_t)f2bf(v3) << 16);
                *(uint2*)(Cb2 + (size_t)row * ld2 + (colb - split)) = pk;
            }
        }
    }
}

// ---------------- GATv2 H=6: branchless 1-deep pair loop, srcs = s<<8 (derive *6) ----------------
__global__ __launch_bounds__(128) void gat6_kernel(
    const ushort_t* __restrict__ cat, const float* __restrict__ att,
    const float* __restrict__ bias, const ushort_t* __restrict__ resB,
    ushort_t* __restrict__ outB,
    const int* __restrict__ offsets, const int* __restrict__ srcs, int n)
{
    int wid = (blockIdx.x * blockDim.x + threadIdx.x) >> 6;
    if (wid >= n) return;
    int lane = threadIdx.x & 63;
    int h = lane >> 3, c8 = lane & 7;
    bool hv = h < HH;
    int off = h * 64 + c8 * 8;
    int offL2 = (hv ? off : off - 384) * 2;   // BYTE offset; invalid lanes alias groups 0/1
    int i = wid;
    int beg = __builtin_amdgcn_readfirstlane(offsets[i]);
    int end = __builtin_amdgcn_readfirstlane(offsets[i + 1]);
    int deg = end - beg;
    int P = (deg + 1) >> 1;
    const char* catc = (const char*)cat;

    f32x2 xr2[4], att2[4];
    {
        uint4 v = *(const uint4*)(catc + (size_t)i * 1536 + 768 + offL2);
        bf8cvt2(v, xr2);
    }
#pragma unroll
    for (int j = 0; j < 4; ++j) {
        int o = (offL2 >> 1) + 2 * j;
        att2[j] = (f32x2){att[o] * LOG2E, att[o + 1] * LOG2E};
    }

    float s = 0.0f;
    f32x2 acc2[4];
#pragma unroll
    for (int j = 0; j < 4; ++j) acc2[j] = (f32x2){0.f, 0.f};

    int bA0 = srcs[beg] * 6, bB0 = srcs[beg + 1] * 6;   // s<<8 -> s*1536
    uint4 cA = *(const uint4*)(catc + (size_t)(uint_t)bA0 + offL2);
    uint4 cB = *(const uint4*)(catc + (size_t)(uint_t)bB0 + offL2);
    int iA1 = srcs[beg + 2] * 6, iB1 = srcs[beg + 3] * 6;

    for (int p = 0; p < P; ++p) {
        uint4 nA = cA, nB = cB;
        bool pre = (p + 1 < P);       // uniform branch: skip useless last prefetch
        if (pre) {
            nA = *(const uint4*)(catc + (size_t)(uint_t)iA1 + offL2);
            nB = *(const uint4*)(catc + (size_t)(uint_t)iB1 + offL2);
            iA1 = srcs[beg + 2 * p + 4] * 6;
            iB1 = srcs[beg + 2 * p + 5] * 6;
        }
        f32x2 xlA[4], xlB[4];
        bf8cvt2(cA, xlA);
        bf8cvt2(cB, xlB);
        f32x2 pA2 = (f32x2){0.f, 0.f}, pB2 = (f32x2){0.f, 0.f};
#pragma unroll
        for (int j = 0; j < 4; ++j) {
            f32x2 ta = xlA[j] + xr2[j];
            ta = __builtin_elementwise_max(ta, ta * 0.2f);
            pA2 += ta * att2[j];
            f32x2 tb = xlB[j] + xr2[j];
            tb = __builtin_elementwise_max(tb, tb * 0.2f);
            pB2 += tb * att2[j];
        }
        float pA = pA2.x + pA2.y, pB = pB2.x + pB2.y;
        pA = dppadd<0xB1>(pA);
        pB = dppadd<0xB1>(pB);
        pA = dppadd<0x4E>(pA);
        pB = dppadd<0x4E>(pB);
        pA = dppadd<0x141>(pA);
        pB = dppadd<0x141>(pB);
        float wA = __builtin_amdgcn_exp2f(pA);
        float wB = (2 * p + 1 < deg) ? __builtin_amdgcn_exp2f(pB) : 0.0f;
        s += wA + wB;
        f32x2 wA2 = (f32x2){wA, wA}, wB2 = (f32x2){wB, wB};
#pragma unroll
        for (int j = 0; j < 4; ++j) {
            acc2[j] += wA2 * xlA[j];
            acc2[j] += wB2 * xlB[j];
        }
        cA = nA; cB = nB;
    }

    if (hv) {
        float inv = 1.0f / (s + 1e-16f);
        size_t ob = (size_t)i * HCC + off;
        uint4 rv = *(const uint4*)(resB + ob);
        f32x2 rr[4];
        bf8cvt2(rv, rr);
        ushort_t u[8];
#pragma unroll
        for (int j = 0; j < 4; ++j) {
            float v0 = acc2[j].x * inv + bias[off + 2 * j];
            float v1 = acc2[j].y * inv + bias[off + 2 * j + 1];
            v0 = v0 > 0.0f ? v0 : expm1f(v0);
            v1 = v1 > 0.0f ? v1 : expm1f(v1);
            u[2 * j]     = f2bf(v0 + rr[j].x);
            u[2 * j + 1] = f2bf(v1 + rr[j].y);
        }
        *(uint4*)(outB + ob) = *(uint4*)u;
    }
}

// ---------------- GATv2 H=1: 16-edge (2x8) pair pipeline, gat6-style ----------------
// r8 diagnosis: old 8-edge loop's prefetch slack (~40 VALU) < L2 latency -> exposed
// stalls. Now 2 edge-groups (A,B) per iteration + pair-prefetch of the next 16:
// iterations ceil(deg/16) (~2), 2x the gathers in flight. Tail via masked weights.
// srcs over-reads up to end+31 -> srcs has +32 zeroed pad.
__global__ __launch_bounds__(128) void gat1_kernel(
    const ushort_t* __restrict__ cat, const float* __restrict__ att,
    const float* __restrict__ bias, const float* __restrict__ res,
    float* __restrict__ out,
    const int* __restrict__ offsets, const int* __restrict__ srcs, int n)
{
    int wid = (blockIdx.x * blockDim.x + threadIdx.x) >> 6;
    if (wid >= n) return;
    int lane = threadIdx.x & 63;
    int e8 = lane >> 3, c8 = lane & 7;
    int i = wid;
    int beg = __builtin_amdgcn_readfirstlane(offsets[i]);
    int end = __builtin_amdgcn_readfirstlane(offsets[i + 1]);
    const char* catc = (const char*)cat;

    f32x2 xr2[4], att2[4];
    {
        uint4 v = *(const uint4*)(cat + (size_t)i * 128 + 64 + c8 * 8);
        bf8cvt2(v, xr2);
    }
#pragma unroll
    for (int j = 0; j < 4; ++j)
        att2[j] = (f32x2){att[c8 * 8 + 2 * j] * LOG2E, att[c8 * 8 + 2 * j + 1] * LOG2E};

    float s = 0.0f;
    f32x2 acc2[4];
#pragma unroll
    for (int j = 0; j < 4; ++j) acc2[j] = (f32x2){0.f, 0.f};

    // prologue: groups A (beg+e8) and B (beg+8+e8) in flight
    int pA = beg + e8, pB = beg + 8 + e8;
    bool vA = pA < end, vB = pB < end;
    uint4 a = *(const uint4*)(catc + (size_t)(uint_t)srcs[pA] + c8 * 16);
    uint4 b = *(const uint4*)(catc + (size_t)(uint_t)srcs[pB] + c8 * 16);

    for (int p0 = beg; p0 < end; p0 += 16) {
        uint4 na = a, nb = b;
        bool nvA = false, nvB = false;
        bool pre = (p0 + 16 < end);   // uniform
        if (pre) {
            int qA = p0 + 16 + e8, qB = p0 + 24 + e8;
            nvA = qA < end; nvB = qB < end;
            na = *(const uint4*)(catc + (size_t)(uint_t)srcs[qA] + c8 * 16);
            nb = *(const uint4*)(catc + (size_t)(uint_t)srcs[qB] + c8 * 16);
        }
        f32x2 xlA[4], xlB[4];
        bf8cvt2(a, xlA);
        bf8cvt2(b, xlB);
        f32x2 lA2 = (f32x2){0.f, 0.f}, lB2 = (f32x2){0.f, 0.f};
#pragma unroll
        for (int j = 0; j < 4; ++j) {
            f32x2 ta = xlA[j] + xr2[j];
            ta = __builtin_elementwise_max(ta, ta * 0.2f);
            lA2 += ta * att2[j];
            f32x2 tb = xlB[j] + xr2[j];
            tb = __builtin_elementwise_max(tb, tb * 0.2f);
            lB2 += tb * att2[j];
        }
        float lA = lA2.x + lA2.y, lB = lB2.x + lB2.y;
        lA = dppadd<0xB1>(lA);
        lB = dppadd<0xB1>(lB);
        lA = dppadd<0x4E>(lA);
        lB = dppadd<0x4E>(lB);
        lA = dppadd<0x141>(lA);
        lB = dppadd<0x141>(lB);
        float wA = vA ? __builtin_amdgcn_exp2f(lA) : 0.0f;
        float wB = vB ? __builtin_amdgcn_exp2f(lB) : 0.0f;
        s += wA + wB;
        f32x2 wA2 = (f32x2){wA, wA}, wB2 = (f32x2){wB, wB};
#pragma unroll
        for (int j = 0; j < 4; ++j) {
            acc2[j] += wA2 * xlA[j];
            acc2[j] += wB2 * xlB[j];
        }
        a = na; b = nb; vA = nvA; vB = nvB;
    }

    // cross-group reduce (8 groups of 8 lanes)
    s = dppadd<0x140>(s);
    s += __shfl_xor(s, 16, 64);
    s += __shfl_xor(s, 32, 64);
#pragma unroll
    for (int j = 0; j < 4; ++j) {
        acc2[j].x += __shfl_xor(acc2[j].x, 8, 64);
        acc2[j].y += __shfl_xor(acc2[j].y, 8, 64);
        acc2[j].x += __shfl_xor(acc2[j].x, 16, 64);
        acc2[j].y += __shfl_xor(acc2[j].y, 16, 64);
        acc2[j].x += __shfl_xor(acc2[j].x, 32, 64);
        acc2[j].y += __shfl_xor(acc2[j].y, 32, 64);
    }
    if (e8 == 0) {
        float inv = 1.0f / (s + 1e-16f);
        size_t ob = (size_t)i * CC + c8 * 8;
        float4 r0 = *(const float4*)(res + ob);
        float4 r1 = *(const float4*)(res + ob + 4);
        float rr[8] = {r0.x, r0.y, r0.z, r0.w, r1.x, r1.y, r1.z, r1.w};
        float av[8] = {acc2[0].x, acc2[0].y, acc2[1].x, acc2[1].y,
                       acc2[2].x, acc2[2].y, acc2[3].x, acc2[3].y};
#pragma unroll
        for (int j = 0; j < 8; ++j) {
            float v2 = av[j] * inv + bias[c8 * 8 + j];
            v2 = v2 > 0.0f ? v2 : expm1f(v2);
            av[j] = v2 + rr[j];
        }
        *(float4*)(out + ob) = make_float4(av[0], av[1], av[2], av[3]);
        *(float4*)(out + ob + 4) = make_float4(av[4], av[5], av[6], av[7]);
    }
}

// ---------------- pooling: 4 blocks per group (batch sorted), one atomic per block ----------------
__global__ __launch_bounds__(256) void pool_kernel(const float* __restrict__ h,
                                                   const int* __restrict__ batch,
                                                   float* __restrict__ pooled, int n) {
    int b = blockIdx.x;            // NG*4 blocks
    int g = b >> 2, qd = b & 3;
    int t = threadIdx.x;           // 256
    int w = t >> 6, lane = t & 63;
    int lo = 0, hi = n;
    while (lo < hi) { int mid = (lo + hi) >> 1; if (batch[mid] < g) lo = mid + 1; else hi = mid; }
    int start = lo;
    int hi2 = n;
    while (lo < hi2) { int mid = (lo + hi2) >> 1; if (batch[mid] < g + 1) lo = mid + 1; else hi2 = mid; }
    int endd = lo;
    int len = endd - start;
    int q0 = start + (len * qd) / 4;
    int q1 = start + (len * (qd + 1)) / 4;
    float acc = 0.0f;
    for (int r = q0 + w; r < q1; r += 4)
        acc += h[(size_t)r * 64 + lane];
    __shared__ float red[4][64];
    red[w][lane] = acc;
    __syncthreads();
    if (w == 0) {
        float v2 = red[0][lane] + red[1][lane] + red[2][lane] + red[3][lane];
        atomicAdd(&pooled[g * 64 + lane], v2);
    }
}

// ---------------- dense head: LDS-staged operands ----------------
__global__ __launch_bounds__(256) void head_kernel(const float* __restrict__ pooled,
                            const float* __restrict__ d1w, const float* __restrict__ d1b,
                            const float* __restrict__ bng, const float* __restrict__ bnb,
                            const float* __restrict__ bnm, const float* __restrict__ bnv,
                            const float* __restrict__ d2w, const float* __restrict__ d2b,
                            float* __restrict__ zout) {
    __shared__ float pl[64 * 64];   // 16 KB
    __shared__ float w1[64 * 64];   // 16 KB
    __shared__ float w2[64 * NCC];  // 4 KB
    __shared__ float z1[64 * 64];   // 16 KB
    int t = threadIdx.x;  // 256
    for (int i = t * 4; i < 64 * 64; i += 1024) {
        *(float4*)&pl[i] = *(const float4*)&pooled[i];
        *(float4*)&w1[i] = *(const float4*)&d1w[i];
    }
    for (int i = t * 4; i < 64 * NCC; i += 1024)
        *(float4*)&w2[i] = *(const float4*)&d2w[i];
    __syncthreads();
    for (int idx = t; idx < 64 * 64; idx += 256) {
        int r = idx >> 6, c = idx & 63;
        float acc = d1b[c];
        for (int k = 0; k < 64; ++k) acc += pl[r * 64 + k] * w1[k * 64 + c];
        acc = (acc - bnm[c]) / sqrtf(bnv[c] + 1e-5f) * bng[c] + bnb[c];
        z1[idx] = acc > 0.0f ? acc : 0.0f;
    }
    __syncthreads();
    for (int idx = t; idx < 64 * NCC; idx += 256) {
        int r = idx >> 4, c = idx & 15;
        float acc = d2b[c];
        for (int k = 0; k < 64; ++k) acc += z1[r * 64 + k] * w2[k * NCC + c];
        zout[idx] = acc;
    }
}

// ---------------- launcher ----------------

extern "C" void kernel_launch(void* const* d_in, const int* in_sizes, int n_in,
                              void* d_out, int out_size, void* d_ws, size_t ws_size,
                              hipStream_t stream) {
    const int N = NN, E = EE, C = CC, HC = HCC, NG = NGG;
    const int EN = E + N;

    const float* x     = (const float*)d_in[0];
    const int*   ei    = (const int*)d_in[1];
    const int*   batch = (const int*)d_in[2];
    const float* inp_w = (const float*)d_in[3];
    const float* inp_b = (const float*)d_in[4];
    const float* l0_wl = (const float*)d_in[5];
    const float* l0_bl = (const float*)d_in[6];
    const float* l0_wr = (const float*)d_in[7];
    const float* l0_br = (const float*)d_in[8];
    const float* l0_att = (const float*)d_in[9];
    const float* l0_bias = (const float*)d_in[10];
    const float* l1_wl = (const float*)d_in[11];
    const float* l1_bl = (const float*)d_in[12];
    const float* l1_wr = (const float*)d_in[13];
    const float* l1_br = (const float*)d_in[14];
    const float* l1_att = (const float*)d_in[15];
    const float* l1_bias = (const float*)d_in[16];
    const float* l2_wl = (const float*)d_in[17];
    const float* l2_bl = (const float*)d_in[18];
    const float* l2_wr = (const float*)d_in[19];
    const float* l2_br = (const float*)d_in[20];
    const float* l2_att = (const float*)d_in[21];
    const float* l2_bias = (const float*)d_in[22];
    const float* res_w = (const float*)d_in[23];
    const float* d1_w = (const float*)d_in[24];
    const float* d1_b = (const float*)d_in[25];
    const float* bn_g = (const float*)d_in[26];
    const float* bn_b = (const float*)d_in[27];
    const float* bn_m = (const float*)d_in[28];
    const float* bn_v = (const float*)d_in[29];
    const float* d2_w = (const float*)d_in[30];
    const float* d2_b = (const float*)d_in[31];

    float* out = (float*)d_out;

    char* ws = (char*)d_ws;
    size_t off = 0;
    auto alloc = [&](size_t bytes) -> void* {
        void* p = ws + off;
        off += (bytes + 255) & ~(size_t)255;
        return p;
    };
    ushort_t* bufH_b  = (ushort_t*)alloc((size_t)N * HC * 2);
    ushort_t* cat01_b = (ushort_t*)alloc((size_t)N * 768 * 2 + 2048);
    ushort_t* xres_b  = (ushort_t*)alloc((size_t)N * HC * 2);
    ushort_t* cat2_b  = (ushort_t*)alloc((size_t)N * 128 * 2);
    float*    bufRes  = (float*)alloc((size_t)N * C * 4);
    ushort_t* xb      = (ushort_t*)alloc((size_t)N * IND * 2);
    ushort_t* wBig    = (ushort_t*)alloc((size_t)WBIG * 2);
    ushort_t* wC1     = (ushort_t*)alloc((size_t)WC1 * 2);
    ushort_t* wC2     = (ushort_t*)alloc((size_t)WC2 * 2);
    float*    bBig    = (float*)alloc((size_t)1152 * 4);
    float*    bC1     = (float*)alloc((size_t)768 * 4);
    float*    bC2     = (float*)alloc((size_t)192 * 4);
    int*      counts  = (int*)alloc((size_t)N * 4);
    int*      cursor  = (int*)alloc((size_t)N * 4);
    int*      offsets = (int*)alloc((size_t)(N + 1) * 4);
    int*      srcs    = (int*)alloc((size_t)(EN + 32) * 4);  // s<<8 + 32-entry zeroed pad
    int*      blockSums = (int*)alloc((size_t)256 * 4);
    float*    pooled  = (float*)alloc((size_t)NG * C * 4);

    const int SCAN_NB = (N + 255) / 256;   // 79

    zero_init_kernel<<<(N + 255) / 256, 256, 0, stream>>>(counts, srcs + EN,
                                                          pooled, N, NG * C);
    count_kernel<<<(E + 255) / 256, 256, 0, stream>>>(ei, counts, E);
    scan_local_kernel<<<SCAN_NB, 256, 0, stream>>>(counts, offsets, blockSums, N);
    scan_fixup_kernel<<<SCAN_NB, 256, 0, stream>>>(blockSums, offsets, cursor, N, SCAN_NB);
    fill_kernel<<<(EN + 255) / 256, 256, 0, stream>>>(ei, cursor, srcs, E, N);
    prep_kernel<<<(PREP_TOTAL + 255) / 256, 256, 0, stream>>>(
        x, inp_w, l0_wl, l0_wr, l1_wl, l1_wr, l2_wl, l2_wr, res_w,
        inp_b, l0_bl, l0_br, l1_bl, l1_br, l2_bl, l2_br,
        wBig, wC1, wC2, xb, bBig, bC1, bC2);

    int mtiles = (N + 127) / 128;      // 157
    dim3 gblk(128);
    int gatBlocks = (N * 64 + 127) / 128;

    // fused: [x_res | l0_xl | l0_xr] = xb @ wBig (bf16 out; split at 384). 1413 blocks.
    gemm_mfma<<<dim3(mtiles, 9), dim3(256), 0, stream>>>(xb, wBig, bBig,
        nullptr, xres_b, HC, cat01_b, 768, 384, N, 1152, IND);
    gat6_kernel<<<gatBlocks, gblk, 0, stream>>>(cat01_b, l0_att, l0_bias,
                                                xres_b, bufH_b, offsets, srcs, N);
    // layer 1: [l1_xl | l1_xr] = h0 @ wC1. 942 blocks.
    gemm_mfma<<<dim3(mtiles, 6), dim3(256), 0, stream>>>(bufH_b, wC1, bC1,
        nullptr, nullptr, 0, cat01_b, 768, 0, N, 768, HC);
    gat6_kernel<<<gatBlocks, gblk, 0, stream>>>(cat01_b, l1_att, l1_bias,
                                                bufH_b, bufH_b, offsets, srcs, N);
    // fused: [res | l2_xl | l2_xr] = h1 @ wC2 (res fp32, rest bf16). 314 blocks.
    gemm_mfma<<<dim3(mtiles, 2), dim3(256), 0, stream>>>(bufH_b, wC2, bC2,
        bufRes, nullptr, C, cat2_b, 128, 64, N, 192, HC);
    gat1_kernel<<<gatBlocks, gblk, 0, stream>>>(cat2_b, l2_att, l2_bias,
                                                bufRes, out, offsets, srcs, N);
    // pooling + head
    pool_kernel<<<NG * 4, 256, 0, stream>>>(out, batch, pooled, N);
    head_kernel<<<1, 256, 0, stream>>>(pooled, d1_w, d1_b, bn_g, bn_b, bn_m, bn_v,
                                       d2_w, d2_b, out + (size_t)N * C);
}